// Round 14
// baseline (571.478 us; speedup 1.0000x reference)
//
#include <hip/hip_runtime.h>
#include <hip/hip_bf16.h>

#define BN_EPS 1e-5f

typedef __attribute__((ext_vector_type(8))) short bf16x8;
typedef __attribute__((ext_vector_type(4))) float f32x4;

__device__ __forceinline__ short f2b(float f) {
    __hip_bfloat16 h = __float2bfloat16(f);
    return *reinterpret_cast<short*>(&h);
}
__device__ __forceinline__ float bu2f(unsigned short u) {
    return __uint_as_float(((unsigned int)u) << 16);
}
__device__ __forceinline__ float lo16(unsigned int v) { return __uint_as_float(v << 16); }
__device__ __forceinline__ float hi16(unsigned int v) { return __uint_as_float(v & 0xffff0000u); }

#define CAPP 1280   /* records per (slot,bucket) cell: mean 1024 + 8 sigma */
#define NBC  256    /* allocated bucket slots (N <= 131072) */

// ---------------- fused prep: flag probe | weight transpose | x->bf16 ----------------
__global__ void k_prep(const int* __restrict__ ei, int* __restrict__ flag,
                       const float* __restrict__ W1, const float* __restrict__ W2,
                       const float* __restrict__ Wm, short* __restrict__ w1t,
                       short* __restrict__ w2t, short* __restrict__ wmt,
                       const float* __restrict__ x, unsigned short* __restrict__ xb,
                       int total4x) {
    int gb = blockIdx.x;
    if (gb == 0) {
        __shared__ int any;
        if (threadIdx.x == 0) any = 0;
        __syncthreads();
        if (ei[2 * threadIdx.x + 1] != 0) atomicOr(&any, 1);
        __syncthreads();
        if (threadIdx.x == 0) *flag = (any == 0);  // all-high-words-zero => int64
    } else if (gb <= 288) {
        int idx = (gb - 1) * 256 + threadIdx.x;
        if (idx < 128 * 64) {
            int c = idx >> 6, k = idx & 63;
            w1t[idx] = f2b(W1[k * 128 + c]);
        } else if (idx < 128 * 64 + 128 * 128) {
            int i = idx - 128 * 64; int c = i >> 7, k = i & 127;
            w2t[i] = f2b(W2[k * 128 + c]);
        } else if (idx < 128 * 64 + 128 * 128 + 128 * 384) {
            int i = idx - (128 * 64 + 128 * 128); int c = i / 384, k = i % 384;
            wmt[i] = f2b(Wm[k * 128 + c]);
        }
    } else {
        int i = (gb - 289) * 256 + threadIdx.x;
        if (i >= total4x) return;
        float4 v = ((const float4*)x)[i];
        ushort4 o;
        o.x = (unsigned short)f2b(v.x);
        o.y = (unsigned short)f2b(v.y);
        o.z = (unsigned short)f2b(v.z);
        o.w = (unsigned short)f2b(v.w);
        ((ushort4*)xb)[i] = o;
    }
}

// ---------------- pass 1: partition edges into (slot, dst>>9) cells ----------------
// Per-BUCKET cursors make a line's 8 record-writes temporally adjacent (cursor
// adjacency == temporal adjacency) and slot-affinity keeps them on ~one XCD.
// rec.x = src | dst_local<<17 (src < 2^17); rec.y = f32 w (full precision).
__global__ void k_part(const int* __restrict__ ei, const float* __restrict__ ew,
                       const int* __restrict__ flag, int* __restrict__ pcur,
                       int2* __restrict__ part, int E, int NB) {
    int e = blockIdx.x * 256 + threadIdx.x;
    if (e >= E) return;
    int slot = blockIdx.x & 7;
    int d, s;
    if (*flag) { s = ei[2 * e]; d = ei[2 * E + 2 * e]; }
    else       { s = ei[e];     d = ei[E + e]; }
    int b = d >> 9;
    int cell = slot * NB + b;
    int pos = atomicAdd(&pcur[cell], 1);
    if (pos >= CAPP) return;  // mean 1024 + 8 sigma headroom: statistically unreachable
    int2 rec;
    rec.x = s | ((d & 511) << 17);
    rec.y = __float_as_int(ew[e]);
    part[(size_t)cell * CAPP + pos] = rec;
}

// ---------------- bucket-base scan (1 block; NB <= 256) ----------------
__global__ void k_bscan(const int* __restrict__ pcur, int* __restrict__ bbase, int NB) {
    __shared__ int lds[256];
    int t = threadIdx.x;
    int tot = 0;
    if (t < NB)
        for (int s = 0; s < 8; ++s) tot += min(pcur[s * NB + t], CAPP);
    lds[t] = tot;
    __syncthreads();
    for (int off = 1; off < 256; off <<= 1) {
        int v = (t >= off) ? lds[t - off] : 0;
        __syncthreads();
        lds[t] += v;
        __syncthreads();
    }
    if (t < NB) bbase[t] = lds[t] - tot;  // exclusive
}

// ---------------- pass 2a: per-bucket histogram -> rowptr/rowend/dinv ----------------
__global__ __launch_bounds__(256) void k_bstats(const int2* __restrict__ part,
        const int* __restrict__ pcur, const int* __restrict__ bbase,
        int* __restrict__ rowptr, int* __restrict__ rowend, float* __restrict__ dinv,
        int N, int NB) {
    __shared__ int cnt[512];
    __shared__ float deg[512];
    __shared__ int scn[512];
    int b = blockIdx.x;
    int t = threadIdx.x;
    cnt[t] = 0; cnt[t + 256] = 0;
    deg[t] = 0.f; deg[t + 256] = 0.f;
    __syncthreads();
    for (int slot = 0; slot < 8; ++slot) {
        int n = min(pcur[slot * NB + b], CAPP);
        const int2* cell = part + (size_t)(slot * NB + b) * CAPP;
        for (int i = t; i < n; i += 256) {
            int2 r = cell[i];
            int dl = (unsigned)r.x >> 17;
            atomicAdd(&cnt[dl], 1);
            atomicAdd(&deg[dl], __int_as_float(r.y));
        }
    }
    __syncthreads();
    scn[t] = cnt[t]; scn[t + 256] = cnt[t + 256];
    __syncthreads();
    for (int off = 1; off < 512; off <<= 1) {
        int v0 = (t >= off) ? scn[t - off] : 0;
        int i1 = t + 256;
        int v1 = (i1 >= off) ? scn[i1 - off] : 0;
        __syncthreads();
        scn[t] += v0; scn[i1] += v1;
        __syncthreads();
    }
    int base = bbase[b];
    for (int l = t; l < 512; l += 256) {
        int node = (b << 9) + l;
        if (node < N) {
            int rp = base + scn[l] - cnt[l];
            rowptr[node] = rp;
            rowend[node] = rp + cnt[l];
            dinv[node] = rsqrtf(deg[l] + 1.0f);
        }
    }
}

// ---------------- pass 2b: per-bucket scatter into final CSR {src, norm} ----------------
__global__ __launch_bounds__(256) void k_bsort(const int2* __restrict__ part,
        const int* __restrict__ pcur, const int* __restrict__ rowptr,
        const float* __restrict__ dinvArr, int2* __restrict__ ecsr, int N, int NB) {
    __shared__ int lcur[512];
    __shared__ float ldinv[512];
    int b = blockIdx.x;
    int t = threadIdx.x;
    for (int l = t; l < 512; l += 256) {
        int node = (b << 9) + l;
        lcur[l] = (node < N) ? rowptr[node] : 0;
        ldinv[l] = (node < N) ? dinvArr[node] : 0.f;
    }
    __syncthreads();
    for (int slot = 0; slot < 8; ++slot) {
        int n = min(pcur[slot * NB + b], CAPP);
        const int2* cell = part + (size_t)(slot * NB + b) * CAPP;
        for (int i = t; i < n; i += 256) {
            int2 r = cell[i];
            int dl = (unsigned)r.x >> 17;
            int s = r.x & 0x1FFFF;
            float w = __int_as_float(r.y);
            int pos = atomicAdd(&lcur[dl], 1);
            int2 o;
            o.x = s;
            o.y = __float_as_int(dinvArr[s] * w * ldinv[dl]);
            ecsr[pos] = o;
        }
    }
}

// ---------------- hybrid MFMA GEMM: B staged in LDS per 128-K chunk, A direct ----------------
// MODE 0: K=64  A=agg0 bf16; out bf16 + bias eb (b1); fused BN stats -> stats
// MODE 1: K=128 A=h1c bf16 + BN(stats,g,be)+ReLU in-reg; out bf16
// MODE 2: K=384 virtual (BN2ReLU(h2c) | dist-feat | degf-feat); out f32 + bias eb (bm)
template <int K, int MODE>
__global__ __launch_bounds__(256) void k_gemm(
        const unsigned short* __restrict__ A, const short* __restrict__ Bt,
        float* __restrict__ stats, const float* __restrict__ g,
        const float* __restrict__ be, const float* __restrict__ dist,
        const float* __restrict__ degf, const float* __restrict__ Wd,
        const float* __restrict__ bd, const float* __restrict__ Wg,
        const float* __restrict__ bg, const float* __restrict__ eb,
        void* __restrict__ out, int N, float invN) {
    constexpr int CH = (K < 128) ? K : 128;
    __shared__ short Bs[128][CH + 8];
    __shared__ float sc[128], sh[128];
    __shared__ float st0[128], st1[128];
    const int t = threadIdx.x;
    const int lane = t & 63;
    const int wave = t >> 6;
    const int rl = lane & 15;
    const int kg = lane >> 4;
    const int r0 = blockIdx.x * 128;

    if (MODE >= 1) {
        if (t < 128) {
            float mean = stats[t] * invN;
            float var = stats[128 + t] * invN - mean * mean;
            float scale = g[t] * rsqrtf(var + BN_EPS);
            sc[t] = scale;
            sh[t] = be[t] - mean * scale;
        }
    }
    if (MODE == 0) {
        if (t < 128) { st0[t] = 0.f; st1[t] = 0.f; }
    }

    f32x4 acc[2][8];
#pragma unroll
    for (int m = 0; m < 2; ++m)
#pragma unroll
        for (int n = 0; n < 8; ++n) acc[m][n] = (f32x4){0.f, 0.f, 0.f, 0.f};

    const int AST = (MODE == 0) ? 64 : 128;
    const int rowbase = r0 + wave * 32 + rl;

    for (int kc = 0; kc < K; kc += CH) {
        if (kc > 0) __syncthreads();
        {
            int c = t >> 1;
            int hb = (t & 1) * (CH / 2);
            const short* wrow = Bt + (size_t)c * K + kc + hb;
#pragma unroll
            for (int q = 0; q < CH / 16; ++q)
                *(int4*)&Bs[c][hb + q * 8] = ((const int4*)wrow)[q];
        }
        __syncthreads();
#pragma unroll
        for (int kt0 = 0; kt0 < CH; kt0 += 32) {
            const int kt = kc + kt0;
            const int k0 = kt + kg * 8;
            const int kl0 = kt0 + kg * 8;
            bf16x8 a[2];
#pragma unroll
            for (int m = 0; m < 2; ++m) {
                const int row = rowbase + m * 16;
                union { int4 q; unsigned short s[8]; } u;
                if (MODE == 2 && kt >= 128) {
                    if (row < N) {
                        const float* Wv; const float* bv; float sx; int cb;
                        if (kt >= 256) { Wv = Wg; bv = bg; sx = degf[row]; cb = k0 - 256; }
                        else           { Wv = Wd; bv = bd; sx = dist[row]; cb = k0 - 128; }
#pragma unroll
                        for (int j = 0; j < 8; ++j)
                            u.s[j] = (unsigned short)f2b(fmaxf(0.f, sx * Wv[cb + j] + bv[cb + j]));
                    } else u.q = (int4){0, 0, 0, 0};
                } else if (MODE == 0) {
                    u.q = (row < N) ? *(const int4*)(A + (size_t)row * AST + k0)
                                    : (int4){0, 0, 0, 0};
                } else {
                    if (row < N) {
                        union { int4 q; unsigned short s[8]; } raw;
                        raw.q = *(const int4*)(A + (size_t)row * AST + k0);
#pragma unroll
                        for (int j = 0; j < 8; ++j)
                            u.s[j] = (unsigned short)f2b(
                                fmaxf(0.f, bu2f(raw.s[j]) * sc[k0 + j] + sh[k0 + j]));
                    } else u.q = (int4){0, 0, 0, 0};
                }
                a[m] = *reinterpret_cast<bf16x8*>(&u);
            }
#pragma unroll
            for (int n = 0; n < 8; ++n) {
                bf16x8 b = *reinterpret_cast<const bf16x8*>(&Bs[n * 16 + rl][kl0]);
                acc[0][n] = __builtin_amdgcn_mfma_f32_16x16x32_bf16(a[0], b, acc[0][n], 0, 0, 0);
                acc[1][n] = __builtin_amdgcn_mfma_f32_16x16x32_bf16(a[1], b, acc[1][n], 0, 0, 0);
            }
        }
    }

    // epilogue (C/D: col=lane&15, row=(lane>>4)*4+reg; m89-verified)
    const int rbase = r0 + wave * 32 + kg * 4;
#pragma unroll
    for (int n = 0; n < 8; ++n) {
        int col = n * 16 + rl;
        float bias = (MODE != 1) ? eb[col] : 0.f;
        float sl = 0.f, ql = 0.f;
#pragma unroll
        for (int m = 0; m < 2; ++m) {
#pragma unroll
            for (int j = 0; j < 4; ++j) {
                int row = rbase + m * 16 + j;
                if (row < N) {
                    float val = acc[m][n][j] + bias;
                    if (MODE == 2) {
                        ((float*)out)[(size_t)row * 128 + col] = val;
                    } else {
                        ((unsigned short*)out)[(size_t)row * 128 + col] = (unsigned short)f2b(val);
                        if (MODE == 0) { sl += val; ql += val * val; }
                    }
                }
            }
        }
        if (MODE == 0) {
            atomicAdd(&st0[col], sl);
            atomicAdd(&st1[col], ql);
        }
    }
    if (MODE == 0) {
        __syncthreads();
        if (t < 128) {
            atomicAdd(&stats[t], st0[t]);
            atomicAdd(&stats[128 + t], st1[t]);
        }
    }
}

// ---------------- CSR gathers ----------------
__global__ void k_gather64(const unsigned short* __restrict__ xb, const int2* __restrict__ ecsr,
                           const int* __restrict__ rowptr, const int* __restrict__ rowend,
                           const float* __restrict__ dinv, unsigned short* __restrict__ agg0,
                           int N) {
    int node = blockIdx.x * 4 + (threadIdx.x >> 6);
    if (node >= N) return;
    int lane = threadIdx.x & 63;
    int start = rowptr[node], end = rowend[node];
    float di = dinv[node];
    float ax = di * di * bu2f(xb[(size_t)node * 64 + lane]);
    int j = start;
    for (; j + 8 <= end; j += 8) {
        float a0 = 0.f, a1 = 0.f;
#pragma unroll
        for (int u = 0; u < 8; u += 2) {
            int2 ea = ecsr[j + u], eb2 = ecsr[j + u + 1];
            a0 += __int_as_float(ea.y)  * bu2f(xb[(size_t)ea.x  * 64 + lane]);
            a1 += __int_as_float(eb2.y) * bu2f(xb[(size_t)eb2.x * 64 + lane]);
        }
        ax += a0 + a1;
    }
    for (; j < end; ++j) {
        int2 e = ecsr[j];
        ax += __int_as_float(e.y) * bu2f(xb[(size_t)e.x * 64 + lane]);
    }
    agg0[(size_t)node * 64 + lane] = (unsigned short)f2b(ax);
}

__global__ void k_gather128b(const unsigned int* __restrict__ t2, const int2* __restrict__ ecsr,
                             const int* __restrict__ rowptr, const int* __restrict__ rowend,
                             const float* __restrict__ dinv, const float* __restrict__ bias,
                             unsigned int* __restrict__ h2c, int N) {
    int node = blockIdx.x * 4 + (threadIdx.x >> 6);
    if (node >= N) return;
    int lane = threadIdx.x & 63;
    int start = rowptr[node], end = rowend[node];
    float di = dinv[node];
    float sl = di * di;
    unsigned int hv = t2[(size_t)node * 64 + lane];
    float2 bv = ((const float2*)bias)[lane];
    float ax = sl * lo16(hv) + bv.x;
    float ay = sl * hi16(hv) + bv.y;
    int j = start;
    for (; j + 16 <= end; j += 16) {
        int2 e[16]; unsigned int v[16];
#pragma unroll
        for (int u = 0; u < 16; ++u) e[u] = ecsr[j + u];
#pragma unroll
        for (int u = 0; u < 16; ++u) v[u] = t2[(size_t)e[u].x * 64 + lane];
#pragma unroll
        for (int u = 0; u < 16; ++u) {
            float w = __int_as_float(e[u].y);
            ax += w * lo16(v[u]);
            ay += w * hi16(v[u]);
        }
    }
    for (; j + 4 <= end; j += 4) {
        int2 e[4]; unsigned int v[4];
#pragma unroll
        for (int u = 0; u < 4; ++u) e[u] = ecsr[j + u];
#pragma unroll
        for (int u = 0; u < 4; ++u) v[u] = t2[(size_t)e[u].x * 64 + lane];
#pragma unroll
        for (int u = 0; u < 4; ++u) {
            float w = __int_as_float(e[u].y);
            ax += w * lo16(v[u]);
            ay += w * hi16(v[u]);
        }
    }
    for (; j < end; ++j) {
        int2 e = ecsr[j];
        float w = __int_as_float(e.y);
        unsigned int v = t2[(size_t)e.x * 64 + lane];
        ax += w * lo16(v);
        ay += w * hi16(v);
    }
    unsigned int packed = (unsigned int)(unsigned short)f2b(ax) |
                          ((unsigned int)(unsigned short)f2b(ay) << 16);
    h2c[(size_t)node * 64 + lane] = packed;
}

// ---------------- BN2 stats: vectorized partials + final reduce ----------------
__global__ __launch_bounds__(256) void k_bn_partial(const uint4* __restrict__ h,
                                                    float* __restrict__ part, int total4) {
    __shared__ float sm[256];
    sm[threadIdx.x] = 0.f;
    __syncthreads();
    float s[8], q[8];
#pragma unroll
    for (int j = 0; j < 8; ++j) { s[j] = 0.f; q[j] = 0.f; }
    int stride = gridDim.x * 256;
    for (int i = blockIdx.x * 256 + threadIdx.x; i < total4; i += stride) {
        uint4 v = h[i];
        float a;
        a = lo16(v.x); s[0] += a; q[0] += a * a;
        a = hi16(v.x); s[1] += a; q[1] += a * a;
        a = lo16(v.y); s[2] += a; q[2] += a * a;
        a = hi16(v.y); s[3] += a; q[3] += a * a;
        a = lo16(v.z); s[4] += a; q[4] += a * a;
        a = hi16(v.z); s[5] += a; q[5] += a * a;
        a = lo16(v.w); s[6] += a; q[6] += a * a;
        a = hi16(v.w); s[7] += a; q[7] += a * a;
    }
    int c0 = 8 * (threadIdx.x & 15);
#pragma unroll
    for (int j = 0; j < 8; ++j) {
        atomicAdd(&sm[c0 + j], s[j]);
        atomicAdd(&sm[128 + c0 + j], q[j]);
    }
    __syncthreads();
    part[blockIdx.x * 256 + threadIdx.x] = sm[threadIdx.x];
}

__global__ void k_bn_reduce(const float* __restrict__ part, float* __restrict__ stats, int nb) {
    int t = threadIdx.x;
    float acc = 0.f;
#pragma unroll 4
    for (int b = 0; b < nb; ++b) acc += part[b * 256 + t];
    stats[t] = acc;
}

extern "C" void kernel_launch(void* const* d_in, const int* in_sizes, int n_in,
                              void* d_out, int out_size, void* d_ws, size_t ws_size,
                              hipStream_t stream) {
    const float* x    = (const float*)d_in[0];
    const int*   ei   = (const int*)d_in[1];
    const float* ew   = (const float*)d_in[2];
    const float* dist = (const float*)d_in[3];
    const float* degf = (const float*)d_in[4];
    const float* W1   = (const float*)d_in[5];
    const float* b1   = (const float*)d_in[6];
    const float* W2   = (const float*)d_in[7];
    const float* b2   = (const float*)d_in[8];
    const float* g1   = (const float*)d_in[9];
    const float* be1  = (const float*)d_in[10];
    const float* g2   = (const float*)d_in[11];
    const float* be2  = (const float*)d_in[12];
    const float* Wd   = (const float*)d_in[13];
    const float* bd   = (const float*)d_in[14];
    const float* Wg   = (const float*)d_in[15];
    const float* bg   = (const float*)d_in[16];
    const float* Wm   = (const float*)d_in[17];
    const float* bm   = (const float*)d_in[18];

    const int IN = 64;
    const int N = in_sizes[0] / IN;   // 100000
    const int E = in_sizes[1] / 2;    // 1600000
    const int NB = (N + 511) >> 9;    // 196 buckets (<= NBC)

    // ws layout (4B words):
    int*   pcur   = (int*)d_ws;                                      // [8*NBC]
    float* stats  = (float*)(pcur + 8 * NBC);                        // [512]
    int*   flag   = (int*)(stats + 512);
    int*   bbase  = flag + 32;                                       // [NBC]
    int*   rowptr = bbase + NBC;                                     // [N]
    int*   rowend = rowptr + N;                                      // [N]
    float* dinv   = (float*)(rowend + N);                            // [N]
    int2*  partb  = (int2*)(dinv + N);                               // [8*NBC*CAPP] int2 (21 MB)
    int2*  ecsr   = partb + (size_t)8 * NBC * CAPP;                  // [E] int2
    unsigned int*   h2c  = (unsigned int*)(ecsr + E);                // N*128 bf16
    unsigned short* agg0 = (unsigned short*)(h2c + (size_t)N * 64);  // N*64 bf16
    unsigned short* xb   = agg0 + (size_t)N * 64;                    // N*64 bf16
    short* w1t    = (short*)(xb + (size_t)N * 64);                   // [128][64]
    short* w2t    = w1t + 128 * 64;                                  // [128][128]
    short* wmt    = w2t + 128 * 128;                                 // [128][384]
    float* bnpart = (float*)(wmt + 128 * 384);                       // [512][256]

    // d_out time-share (bf16 staging, overwritten by final f32 GEMM)
    unsigned short* h1c = (unsigned short*)d_out;                    // N*128 bf16
    unsigned int*   t2  = (unsigned int*)d_out + (size_t)N * 64;     // N*128 bf16 pairs

    hipMemsetAsync(pcur, 0, (8 * NBC + 512) * sizeof(int), stream);  // pcur + stats

    const int nchunkE = (E + 255) / 256;
    const int nbG  = (N + 3) / 4;
    const int nbPrep = 1 + 288 + (N * 16 + 255) / 256;

    k_prep<<<nbPrep, 256, 0, stream>>>(ei, flag, W1, W2, Wm, w1t, w2t, wmt, x, xb, N * 16);
    k_part<<<nchunkE, 256, 0, stream>>>(ei, ew, flag, pcur, partb, E, NB);
    k_bscan<<<1, 256, 0, stream>>>(pcur, bbase, NB);
    k_bstats<<<NB, 256, 0, stream>>>(partb, pcur, bbase, rowptr, rowend, dinv, N, NB);
    k_bsort<<<NB, 256, 0, stream>>>(partb, pcur, rowptr, dinv, ecsr, N, NB);

    const int nbGe = (N + 127) / 128;
    const int nbP  = 512;
    const float invN = 1.0f / (float)N;

    // layer 1: agg0 = A_hat @ x; h1c = agg0 @ W1 + b1 (stats1 fused in epilogue)
    k_gather64<<<nbG, 256, 0, stream>>>(xb, ecsr, rowptr, rowend, dinv, agg0, N);
    k_gemm<64, 0><<<nbGe, 256, 0, stream>>>(agg0, w1t, stats, nullptr, nullptr, nullptr,
                                            nullptr, nullptr, nullptr, nullptr, nullptr,
                                            b1, h1c, N, invN);

    // layer 2: t2 = BN1ReLU(h1c) @ W2; h2c = A_hat @ t2 + b2; stats2 (two-stage)
    k_gemm<128, 1><<<nbGe, 256, 0, stream>>>(h1c, w2t, stats, g1, be1, nullptr,
                                             nullptr, nullptr, nullptr, nullptr, nullptr,
                                             nullptr, t2, N, invN);
    k_gather128b<<<nbG, 256, 0, stream>>>(t2, ecsr, rowptr, rowend, dinv, b2, h2c, N);
    k_bn_partial<<<nbP, 256, 0, stream>>>((const uint4*)h2c, bnpart, N * 16);
    k_bn_reduce<<<1, 256, 0, stream>>>(bnpart, stats + 256, nbP);

    // final: [BN2ReLU(h2c) | relu(dist*Wd+bd) | relu(degf*Wg+bg)] @ Wm + bm -> d_out f32
    k_gemm<384, 2><<<nbGe, 256, 0, stream>>>((const unsigned short*)h2c, wmt, stats + 256,
                                             g2, be2, dist, degf, Wd, bd, Wg, bg,
                                             bm, d_out, N, invN);
}

// Round 15
// 435.760 us; speedup vs baseline: 1.3115x; 1.3115x over previous
//
#include <hip/hip_runtime.h>
#include <hip/hip_bf16.h>

#define BN_EPS 1e-5f

typedef __attribute__((ext_vector_type(8))) short bf16x8;
typedef __attribute__((ext_vector_type(4))) float f32x4;

__device__ __forceinline__ short f2b(float f) {
    __hip_bfloat16 h = __float2bfloat16(f);
    return *reinterpret_cast<short*>(&h);
}
__device__ __forceinline__ float bu2f(unsigned short u) {
    return __uint_as_float(((unsigned int)u) << 16);
}
__device__ __forceinline__ float lo16(unsigned int v) { return __uint_as_float(v << 16); }
__device__ __forceinline__ float hi16(unsigned int v) { return __uint_as_float(v & 0xffff0000u); }

#define CAPP 1280     /* records per (slot,bucket) cell: mean 1024 + 8 sigma */
#define NBC  256      /* allocated bucket slots (N <= 131072) */
#define PST  16       /* cursor padding: 16 ints = 64 B = one cache line per cursor */

// ---------------- fused prep: flag probe | weight transpose | x->bf16 ----------------
__global__ void k_prep(const int* __restrict__ ei, int* __restrict__ flag,
                       const float* __restrict__ W1, const float* __restrict__ W2,
                       const float* __restrict__ Wm, short* __restrict__ w1t,
                       short* __restrict__ w2t, short* __restrict__ wmt,
                       const float* __restrict__ x, unsigned short* __restrict__ xb,
                       int total4x) {
    int gb = blockIdx.x;
    if (gb == 0) {
        __shared__ int any;
        if (threadIdx.x == 0) any = 0;
        __syncthreads();
        if (ei[2 * threadIdx.x + 1] != 0) atomicOr(&any, 1);
        __syncthreads();
        if (threadIdx.x == 0) *flag = (any == 0);  // all-high-words-zero => int64
    } else if (gb <= 288) {
        int idx = (gb - 1) * 256 + threadIdx.x;
        if (idx < 128 * 64) {
            int c = idx >> 6, k = idx & 63;
            w1t[idx] = f2b(W1[k * 128 + c]);
        } else if (idx < 128 * 64 + 128 * 128) {
            int i = idx - 128 * 64; int c = i >> 7, k = i & 127;
            w2t[i] = f2b(W2[k * 128 + c]);
        } else if (idx < 128 * 64 + 128 * 128 + 128 * 384) {
            int i = idx - (128 * 64 + 128 * 128); int c = i / 384, k = i % 384;
            wmt[i] = f2b(Wm[k * 128 + c]);
        }
    } else {
        int i = (gb - 289) * 256 + threadIdx.x;
        if (i >= total4x) return;
        float4 v = ((const float4*)x)[i];
        ushort4 o;
        o.x = (unsigned short)f2b(v.x);
        o.y = (unsigned short)f2b(v.y);
        o.z = (unsigned short)f2b(v.z);
        o.w = (unsigned short)f2b(v.w);
        ((ushort4*)xb)[i] = o;
    }
}

// ---------------- pass 1: partition edges into (slot, dst>>9) cells ----------------
// Per-bucket cursors (cursor adjacency == temporal adjacency for record lines).
// Each cursor PADDED to its own cache line: same-line atomic chains drop from
// 16K/line (R14: 98 shared lines, ~200us) to ~1000/cell on a private line.
__global__ void k_part(const int* __restrict__ ei, const float* __restrict__ ew,
                       const int* __restrict__ flag, int* __restrict__ pcur,
                       int2* __restrict__ part, int E, int NB) {
    int e = blockIdx.x * 256 + threadIdx.x;
    if (e >= E) return;
    int slot = blockIdx.x & 7;
    int d, s;
    if (*flag) { s = ei[2 * e]; d = ei[2 * E + 2 * e]; }
    else       { s = ei[e];     d = ei[E + e]; }
    int b = d >> 9;
    int cell = slot * NB + b;
    int pos = atomicAdd(&pcur[cell * PST], 1);
    if (pos >= CAPP) return;  // mean 1024 + 8 sigma headroom: statistically unreachable
    int2 rec;
    rec.x = s | ((d & 511) << 17);
    rec.y = __float_as_int(ew[e]);
    part[(size_t)cell * CAPP + pos] = rec;
}

// ---------------- bucket-base scan (1 block; NB <= 256) ----------------
__global__ void k_bscan(const int* __restrict__ pcur, int* __restrict__ bbase, int NB) {
    __shared__ int lds[256];
    int t = threadIdx.x;
    int tot = 0;
    if (t < NB)
        for (int s = 0; s < 8; ++s) tot += min(pcur[(s * NB + t) * PST], CAPP);
    lds[t] = tot;
    __syncthreads();
    for (int off = 1; off < 256; off <<= 1) {
        int v = (t >= off) ? lds[t - off] : 0;
        __syncthreads();
        lds[t] += v;
        __syncthreads();
    }
    if (t < NB) bbase[t] = lds[t] - tot;  // exclusive
}

// ---------------- pass 2a: per-bucket histogram -> rowptr/rowend/dinv ----------------
__global__ __launch_bounds__(256) void k_bstats(const int2* __restrict__ part,
        const int* __restrict__ pcur, const int* __restrict__ bbase,
        int* __restrict__ rowptr, int* __restrict__ rowend, float* __restrict__ dinv,
        int N, int NB) {
    __shared__ int cnt[512];
    __shared__ float deg[512];
    __shared__ int scn[512];
    int b = blockIdx.x;
    int t = threadIdx.x;
    cnt[t] = 0; cnt[t + 256] = 0;
    deg[t] = 0.f; deg[t + 256] = 0.f;
    __syncthreads();
    for (int slot = 0; slot < 8; ++slot) {
        int n = min(pcur[(slot * NB + b) * PST], CAPP);
        const int2* cell = part + (size_t)(slot * NB + b) * CAPP;
        for (int i = t; i < n; i += 256) {
            int2 r = cell[i];
            int dl = (unsigned)r.x >> 17;
            atomicAdd(&cnt[dl], 1);
            atomicAdd(&deg[dl], __int_as_float(r.y));
        }
    }
    __syncthreads();
    scn[t] = cnt[t]; scn[t + 256] = cnt[t + 256];
    __syncthreads();
    for (int off = 1; off < 512; off <<= 1) {
        int v0 = (t >= off) ? scn[t - off] : 0;
        int i1 = t + 256;
        int v1 = (i1 >= off) ? scn[i1 - off] : 0;
        __syncthreads();
        scn[t] += v0; scn[i1] += v1;
        __syncthreads();
    }
    int base = bbase[b];
    for (int l = t; l < 512; l += 256) {
        int node = (b << 9) + l;
        if (node < N) {
            int rp = base + scn[l] - cnt[l];
            rowptr[node] = rp;
            rowend[node] = rp + cnt[l];
            dinv[node] = rsqrtf(deg[l] + 1.0f);
        }
    }
}

// ---------------- pass 2b: per-bucket scatter into final CSR {src, norm} ----------------
__global__ __launch_bounds__(256) void k_bsort(const int2* __restrict__ part,
        const int* __restrict__ pcur, const int* __restrict__ rowptr,
        const float* __restrict__ dinvArr, int2* __restrict__ ecsr, int N, int NB) {
    __shared__ int lcur[512];
    __shared__ float ldinv[512];
    int b = blockIdx.x;
    int t = threadIdx.x;
    for (int l = t; l < 512; l += 256) {
        int node = (b << 9) + l;
        lcur[l] = (node < N) ? rowptr[node] : 0;
        ldinv[l] = (node < N) ? dinvArr[node] : 0.f;
    }
    __syncthreads();
    for (int slot = 0; slot < 8; ++slot) {
        int n = min(pcur[(slot * NB + b) * PST], CAPP);
        const int2* cell = part + (size_t)(slot * NB + b) * CAPP;
        for (int i = t; i < n; i += 256) {
            int2 r = cell[i];
            int dl = (unsigned)r.x >> 17;
            int s = r.x & 0x1FFFF;
            float w = __int_as_float(r.y);
            int pos = atomicAdd(&lcur[dl], 1);
            int2 o;
            o.x = s;
            o.y = __float_as_int(dinvArr[s] * w * ldinv[dl]);
            ecsr[pos] = o;
        }
    }
}

// ---------------- hybrid MFMA GEMM: B staged in LDS per 128-K chunk, A direct ----------------
// MODE 0: K=64  A=agg0 bf16; out bf16 + bias eb (b1); fused BN stats -> stats
// MODE 1: K=128 A=h1c bf16 + BN(stats,g,be)+ReLU in-reg; out bf16
// MODE 2: K=384 virtual (BN2ReLU(h2c) | dist-feat | degf-feat); out f32 + bias eb (bm)
template <int K, int MODE>
__global__ __launch_bounds__(256) void k_gemm(
        const unsigned short* __restrict__ A, const short* __restrict__ Bt,
        float* __restrict__ stats, const float* __restrict__ g,
        const float* __restrict__ be, const float* __restrict__ dist,
        const float* __restrict__ degf, const float* __restrict__ Wd,
        const float* __restrict__ bd, const float* __restrict__ Wg,
        const float* __restrict__ bg, const float* __restrict__ eb,
        void* __restrict__ out, int N, float invN) {
    constexpr int CH = (K < 128) ? K : 128;
    __shared__ short Bs[128][CH + 8];
    __shared__ float sc[128], sh[128];
    __shared__ float st0[128], st1[128];
    const int t = threadIdx.x;
    const int lane = t & 63;
    const int wave = t >> 6;
    const int rl = lane & 15;
    const int kg = lane >> 4;
    const int r0 = blockIdx.x * 128;

    if (MODE >= 1) {
        if (t < 128) {
            float mean = stats[t] * invN;
            float var = stats[128 + t] * invN - mean * mean;
            float scale = g[t] * rsqrtf(var + BN_EPS);
            sc[t] = scale;
            sh[t] = be[t] - mean * scale;
        }
    }
    if (MODE == 0) {
        if (t < 128) { st0[t] = 0.f; st1[t] = 0.f; }
    }

    f32x4 acc[2][8];
#pragma unroll
    for (int m = 0; m < 2; ++m)
#pragma unroll
        for (int n = 0; n < 8; ++n) acc[m][n] = (f32x4){0.f, 0.f, 0.f, 0.f};

    const int AST = (MODE == 0) ? 64 : 128;
    const int rowbase = r0 + wave * 32 + rl;

    for (int kc = 0; kc < K; kc += CH) {
        if (kc > 0) __syncthreads();
        {
            int c = t >> 1;
            int hb = (t & 1) * (CH / 2);
            const short* wrow = Bt + (size_t)c * K + kc + hb;
#pragma unroll
            for (int q = 0; q < CH / 16; ++q)
                *(int4*)&Bs[c][hb + q * 8] = ((const int4*)wrow)[q];
        }
        __syncthreads();
#pragma unroll
        for (int kt0 = 0; kt0 < CH; kt0 += 32) {
            const int kt = kc + kt0;
            const int k0 = kt + kg * 8;
            const int kl0 = kt0 + kg * 8;
            bf16x8 a[2];
#pragma unroll
            for (int m = 0; m < 2; ++m) {
                const int row = rowbase + m * 16;
                union { int4 q; unsigned short s[8]; } u;
                if (MODE == 2 && kt >= 128) {
                    if (row < N) {
                        const float* Wv; const float* bv; float sx; int cb;
                        if (kt >= 256) { Wv = Wg; bv = bg; sx = degf[row]; cb = k0 - 256; }
                        else           { Wv = Wd; bv = bd; sx = dist[row]; cb = k0 - 128; }
#pragma unroll
                        for (int j = 0; j < 8; ++j)
                            u.s[j] = (unsigned short)f2b(fmaxf(0.f, sx * Wv[cb + j] + bv[cb + j]));
                    } else u.q = (int4){0, 0, 0, 0};
                } else if (MODE == 0) {
                    u.q = (row < N) ? *(const int4*)(A + (size_t)row * AST + k0)
                                    : (int4){0, 0, 0, 0};
                } else {
                    if (row < N) {
                        union { int4 q; unsigned short s[8]; } raw;
                        raw.q = *(const int4*)(A + (size_t)row * AST + k0);
#pragma unroll
                        for (int j = 0; j < 8; ++j)
                            u.s[j] = (unsigned short)f2b(
                                fmaxf(0.f, bu2f(raw.s[j]) * sc[k0 + j] + sh[k0 + j]));
                    } else u.q = (int4){0, 0, 0, 0};
                }
                a[m] = *reinterpret_cast<bf16x8*>(&u);
            }
#pragma unroll
            for (int n = 0; n < 8; ++n) {
                bf16x8 b = *reinterpret_cast<const bf16x8*>(&Bs[n * 16 + rl][kl0]);
                acc[0][n] = __builtin_amdgcn_mfma_f32_16x16x32_bf16(a[0], b, acc[0][n], 0, 0, 0);
                acc[1][n] = __builtin_amdgcn_mfma_f32_16x16x32_bf16(a[1], b, acc[1][n], 0, 0, 0);
            }
        }
    }

    // epilogue (C/D: col=lane&15, row=(lane>>4)*4+reg; m89-verified)
    const int rbase = r0 + wave * 32 + kg * 4;
#pragma unroll
    for (int n = 0; n < 8; ++n) {
        int col = n * 16 + rl;
        float bias = (MODE != 1) ? eb[col] : 0.f;
        float sl = 0.f, ql = 0.f;
#pragma unroll
        for (int m = 0; m < 2; ++m) {
#pragma unroll
            for (int j = 0; j < 4; ++j) {
                int row = rbase + m * 16 + j;
                if (row < N) {
                    float val = acc[m][n][j] + bias;
                    if (MODE == 2) {
                        ((float*)out)[(size_t)row * 128 + col] = val;
                    } else {
                        ((unsigned short*)out)[(size_t)row * 128 + col] = (unsigned short)f2b(val);
                        if (MODE == 0) { sl += val; ql += val * val; }
                    }
                }
            }
        }
        if (MODE == 0) {
            atomicAdd(&st0[col], sl);
            atomicAdd(&st1[col], ql);
        }
    }
    if (MODE == 0) {
        __syncthreads();
        if (t < 128) {
            atomicAdd(&stats[t], st0[t]);
            atomicAdd(&stats[128 + t], st1[t]);
        }
    }
}

// ---------------- CSR gathers ----------------
__global__ void k_gather64(const unsigned short* __restrict__ xb, const int2* __restrict__ ecsr,
                           const int* __restrict__ rowptr, const int* __restrict__ rowend,
                           const float* __restrict__ dinv, unsigned short* __restrict__ agg0,
                           int N) {
    int node = blockIdx.x * 4 + (threadIdx.x >> 6);
    if (node >= N) return;
    int lane = threadIdx.x & 63;
    int start = rowptr[node], end = rowend[node];
    float di = dinv[node];
    float ax = di * di * bu2f(xb[(size_t)node * 64 + lane]);
    int j = start;
    for (; j + 8 <= end; j += 8) {
        float a0 = 0.f, a1 = 0.f;
#pragma unroll
        for (int u = 0; u < 8; u += 2) {
            int2 ea = ecsr[j + u], eb2 = ecsr[j + u + 1];
            a0 += __int_as_float(ea.y)  * bu2f(xb[(size_t)ea.x  * 64 + lane]);
            a1 += __int_as_float(eb2.y) * bu2f(xb[(size_t)eb2.x * 64 + lane]);
        }
        ax += a0 + a1;
    }
    for (; j < end; ++j) {
        int2 e = ecsr[j];
        ax += __int_as_float(e.y) * bu2f(xb[(size_t)e.x * 64 + lane]);
    }
    agg0[(size_t)node * 64 + lane] = (unsigned short)f2b(ax);
}

__global__ void k_gather128b(const unsigned int* __restrict__ t2, const int2* __restrict__ ecsr,
                             const int* __restrict__ rowptr, const int* __restrict__ rowend,
                             const float* __restrict__ dinv, const float* __restrict__ bias,
                             unsigned int* __restrict__ h2c, int N) {
    int node = blockIdx.x * 4 + (threadIdx.x >> 6);
    if (node >= N) return;
    int lane = threadIdx.x & 63;
    int start = rowptr[node], end = rowend[node];
    float di = dinv[node];
    float sl = di * di;
    unsigned int hv = t2[(size_t)node * 64 + lane];
    float2 bv = ((const float2*)bias)[lane];
    float ax = sl * lo16(hv) + bv.x;
    float ay = sl * hi16(hv) + bv.y;
    int j = start;
    for (; j + 16 <= end; j += 16) {
        int2 e[16]; unsigned int v[16];
#pragma unroll
        for (int u = 0; u < 16; ++u) e[u] = ecsr[j + u];
#pragma unroll
        for (int u = 0; u < 16; ++u) v[u] = t2[(size_t)e[u].x * 64 + lane];
#pragma unroll
        for (int u = 0; u < 16; ++u) {
            float w = __int_as_float(e[u].y);
            ax += w * lo16(v[u]);
            ay += w * hi16(v[u]);
        }
    }
    for (; j + 4 <= end; j += 4) {
        int2 e[4]; unsigned int v[4];
#pragma unroll
        for (int u = 0; u < 4; ++u) e[u] = ecsr[j + u];
#pragma unroll
        for (int u = 0; u < 4; ++u) v[u] = t2[(size_t)e[u].x * 64 + lane];
#pragma unroll
        for (int u = 0; u < 4; ++u) {
            float w = __int_as_float(e[u].y);
            ax += w * lo16(v[u]);
            ay += w * hi16(v[u]);
        }
    }
    for (; j < end; ++j) {
        int2 e = ecsr[j];
        float w = __int_as_float(e.y);
        unsigned int v = t2[(size_t)e.x * 64 + lane];
        ax += w * lo16(v);
        ay += w * hi16(v);
    }
    unsigned int packed = (unsigned int)(unsigned short)f2b(ax) |
                          ((unsigned int)(unsigned short)f2b(ay) << 16);
    h2c[(size_t)node * 64 + lane] = packed;
}

// ---------------- BN2 stats: vectorized partials + final reduce ----------------
__global__ __launch_bounds__(256) void k_bn_partial(const uint4* __restrict__ h,
                                                    float* __restrict__ part, int total4) {
    __shared__ float sm[256];
    sm[threadIdx.x] = 0.f;
    __syncthreads();
    float s[8], q[8];
#pragma unroll
    for (int j = 0; j < 8; ++j) { s[j] = 0.f; q[j] = 0.f; }
    int stride = gridDim.x * 256;
    for (int i = blockIdx.x * 256 + threadIdx.x; i < total4; i += stride) {
        uint4 v = h[i];
        float a;
        a = lo16(v.x); s[0] += a; q[0] += a * a;
        a = hi16(v.x); s[1] += a; q[1] += a * a;
        a = lo16(v.y); s[2] += a; q[2] += a * a;
        a = hi16(v.y); s[3] += a; q[3] += a * a;
        a = lo16(v.z); s[4] += a; q[4] += a * a;
        a = hi16(v.z); s[5] += a; q[5] += a * a;
        a = lo16(v.w); s[6] += a; q[6] += a * a;
        a = hi16(v.w); s[7] += a; q[7] += a * a;
    }
    int c0 = 8 * (threadIdx.x & 15);
#pragma unroll
    for (int j = 0; j < 8; ++j) {
        atomicAdd(&sm[c0 + j], s[j]);
        atomicAdd(&sm[128 + c0 + j], q[j]);
    }
    __syncthreads();
    part[blockIdx.x * 256 + threadIdx.x] = sm[threadIdx.x];
}

__global__ void k_bn_reduce(const float* __restrict__ part, float* __restrict__ stats, int nb) {
    int t = threadIdx.x;
    float acc = 0.f;
#pragma unroll 4
    for (int b = 0; b < nb; ++b) acc += part[b * 256 + t];
    stats[t] = acc;
}

extern "C" void kernel_launch(void* const* d_in, const int* in_sizes, int n_in,
                              void* d_out, int out_size, void* d_ws, size_t ws_size,
                              hipStream_t stream) {
    const float* x    = (const float*)d_in[0];
    const int*   ei   = (const int*)d_in[1];
    const float* ew   = (const float*)d_in[2];
    const float* dist = (const float*)d_in[3];
    const float* degf = (const float*)d_in[4];
    const float* W1   = (const float*)d_in[5];
    const float* b1   = (const float*)d_in[6];
    const float* W2   = (const float*)d_in[7];
    const float* b2   = (const float*)d_in[8];
    const float* g1   = (const float*)d_in[9];
    const float* be1  = (const float*)d_in[10];
    const float* g2   = (const float*)d_in[11];
    const float* be2  = (const float*)d_in[12];
    const float* Wd   = (const float*)d_in[13];
    const float* bd   = (const float*)d_in[14];
    const float* Wg   = (const float*)d_in[15];
    const float* bg   = (const float*)d_in[16];
    const float* Wm   = (const float*)d_in[17];
    const float* bm   = (const float*)d_in[18];

    const int IN = 64;
    const int N = in_sizes[0] / IN;   // 100000
    const int E = in_sizes[1] / 2;    // 1600000
    const int NB = (N + 511) >> 9;    // 196 buckets (<= NBC)

    // ws layout (4B words):
    int*   pcur   = (int*)d_ws;                                      // [8*NBC*PST] (padded cursors)
    float* stats  = (float*)(pcur + 8 * NBC * PST);                  // [512]
    int*   flag   = (int*)(stats + 512);
    int*   bbase  = flag + 32;                                       // [NBC]
    int*   rowptr = bbase + NBC;                                     // [N]
    int*   rowend = rowptr + N;                                      // [N]
    float* dinv   = (float*)(rowend + N);                            // [N]
    int2*  partb  = (int2*)(dinv + N);                               // [8*NBC*CAPP] int2 (21 MB)
    int2*  ecsr   = partb + (size_t)8 * NBC * CAPP;                  // [E] int2
    unsigned int*   h2c  = (unsigned int*)(ecsr + E);                // N*128 bf16
    unsigned short* agg0 = (unsigned short*)(h2c + (size_t)N * 64);  // N*64 bf16
    unsigned short* xb   = agg0 + (size_t)N * 64;                    // N*64 bf16
    short* w1t    = (short*)(xb + (size_t)N * 64);                   // [128][64]
    short* w2t    = w1t + 128 * 64;                                  // [128][128]
    short* wmt    = w2t + 128 * 128;                                 // [128][384]
    float* bnpart = (float*)(wmt + 128 * 384);                       // [512][256]

    // d_out time-share (bf16 staging, overwritten by final f32 GEMM)
    unsigned short* h1c = (unsigned short*)d_out;                    // N*128 bf16
    unsigned int*   t2  = (unsigned int*)d_out + (size_t)N * 64;     // N*128 bf16 pairs

    hipMemsetAsync(pcur, 0, (8 * NBC * PST + 512) * sizeof(int), stream);  // pcur + stats

    const int nchunkE = (E + 255) / 256;
    const int nbG  = (N + 3) / 4;
    const int nbPrep = 1 + 288 + (N * 16 + 255) / 256;

    k_prep<<<nbPrep, 256, 0, stream>>>(ei, flag, W1, W2, Wm, w1t, w2t, wmt, x, xb, N * 16);
    k_part<<<nchunkE, 256, 0, stream>>>(ei, ew, flag, pcur, partb, E, NB);
    k_bscan<<<1, 256, 0, stream>>>(pcur, bbase, NB);
    k_bstats<<<NB, 256, 0, stream>>>(partb, pcur, bbase, rowptr, rowend, dinv, N, NB);
    k_bsort<<<NB, 256, 0, stream>>>(partb, pcur, rowptr, dinv, ecsr, N, NB);

    const int nbGe = (N + 127) / 128;
    const int nbP  = 512;
    const float invN = 1.0f / (float)N;

    // layer 1: agg0 = A_hat @ x; h1c = agg0 @ W1 + b1 (stats1 fused in epilogue)
    k_gather64<<<nbG, 256, 0, stream>>>(xb, ecsr, rowptr, rowend, dinv, agg0, N);
    k_gemm<64, 0><<<nbGe, 256, 0, stream>>>(agg0, w1t, stats, nullptr, nullptr, nullptr,
                                            nullptr, nullptr, nullptr, nullptr, nullptr,
                                            b1, h1c, N, invN);

    // layer 2: t2 = BN1ReLU(h1c) @ W2; h2c = A_hat @ t2 + b2; stats2 (two-stage)
    k_gemm<128, 1><<<nbGe, 256, 0, stream>>>(h1c, w2t, stats, g1, be1, nullptr,
                                             nullptr, nullptr, nullptr, nullptr, nullptr,
                                             nullptr, t2, N, invN);
    k_gather128b<<<nbG, 256, 0, stream>>>(t2, ecsr, rowptr, rowend, dinv, b2, h2c, N);
    k_bn_partial<<<nbP, 256, 0, stream>>>((const uint4*)h2c, bnpart, N * 16);
    k_bn_reduce<<<1, 256, 0, stream>>>(bnpart, stats + 256, nbP);

    // final: [BN2ReLU(h2c) | relu(dist*Wd+bd) | relu(degf*Wg+bg)] @ Wm + bm -> d_out f32
    k_gemm<384, 2><<<nbGe, 256, 0, stream>>>((const unsigned short*)h2c, wmt, stats + 256,
                                             g2, be2, dist, degf, Wd, bd, Wg, bg,
                                             bm, d_out, N, invN);
}

// Round 16
// 380.472 us; speedup vs baseline: 1.5020x; 1.1453x over previous
//
#include <hip/hip_runtime.h>
#include <hip/hip_bf16.h>

#define BN_EPS 1e-5f

typedef __attribute__((ext_vector_type(8))) short bf16x8;
typedef __attribute__((ext_vector_type(4))) float f32x4;

__device__ __forceinline__ short f2b(float f) {
    __hip_bfloat16 h = __float2bfloat16(f);
    return *reinterpret_cast<short*>(&h);
}
__device__ __forceinline__ float bu2f(unsigned short u) {
    return __uint_as_float(((unsigned int)u) << 16);
}
__device__ __forceinline__ float lo16(unsigned int v) { return __uint_as_float(v << 16); }
__device__ __forceinline__ float hi16(unsigned int v) { return __uint_as_float(v & 0xffff0000u); }

#define CAPP 1280     /* records per (slot,bucket) cell: mean 1024 + 8 sigma */
#define NBC  256      /* allocated bucket slots (N <= 131072) */
#define PST  16       /* cursor padding: 16 ints = 64 B = one cache line per cursor */

// ---------------- fused prep: flag probe | weight transpose | x->bf16 ----------------
__global__ void k_prep(const int* __restrict__ ei, int* __restrict__ flag,
                       const float* __restrict__ W1, const float* __restrict__ W2,
                       const float* __restrict__ Wm, short* __restrict__ w1t,
                       short* __restrict__ w2t, short* __restrict__ wmt,
                       const float* __restrict__ x, unsigned short* __restrict__ xb,
                       int total4x) {
    int gb = blockIdx.x;
    if (gb == 0) {
        __shared__ int any;
        if (threadIdx.x == 0) any = 0;
        __syncthreads();
        if (ei[2 * threadIdx.x + 1] != 0) atomicOr(&any, 1);
        __syncthreads();
        if (threadIdx.x == 0) *flag = (any == 0);  // all-high-words-zero => int64
    } else if (gb <= 288) {
        int idx = (gb - 1) * 256 + threadIdx.x;
        if (idx < 128 * 64) {
            int c = idx >> 6, k = idx & 63;
            w1t[idx] = f2b(W1[k * 128 + c]);
        } else if (idx < 128 * 64 + 128 * 128) {
            int i = idx - 128 * 64; int c = i >> 7, k = i & 127;
            w2t[i] = f2b(W2[k * 128 + c]);
        } else if (idx < 128 * 64 + 128 * 128 + 128 * 384) {
            int i = idx - (128 * 64 + 128 * 128); int c = i / 384, k = i % 384;
            wmt[i] = f2b(Wm[k * 128 + c]);
        }
    } else {
        int i = (gb - 289) * 256 + threadIdx.x;
        if (i >= total4x) return;
        float4 v = ((const float4*)x)[i];
        ushort4 o;
        o.x = (unsigned short)f2b(v.x);
        o.y = (unsigned short)f2b(v.y);
        o.z = (unsigned short)f2b(v.z);
        o.w = (unsigned short)f2b(v.w);
        ((ushort4*)xb)[i] = o;
    }
}

// ---------------- pass 1: partition edges into (slot, dst>>9) cells ----------------
// Block-level claiming: LDS histogram over buckets, ONE global atomic per
// (block,bucket) (~280K total vs 1.6M per-edge), then bucket-grouped record
// writes (runs of ~5 contiguous records) -> line's 8 records come from ~1.5
// temporally-adjacent blocks instead of 8 scattered writers.
__global__ __launch_bounds__(256) void k_part(const int* __restrict__ ei,
        const float* __restrict__ ew, const int* __restrict__ flag,
        int* __restrict__ pcur, int2* __restrict__ part, int E, int NB) {
    __shared__ int lcnt[NBC];
    __shared__ int lbase[NBC];
    int t = threadIdx.x;
    int slot = blockIdx.x & 7;
    for (int i = t; i < NBC; i += 256) lcnt[i] = 0;
    __syncthreads();
    int e0 = blockIdx.x * 1024;
    bool f64 = (*flag != 0);
    int sv[4], bv[4], loc[4]; float wv[4];
#pragma unroll
    for (int q = 0; q < 4; ++q) {
        int e = e0 + q * 256 + t;
        if (e < E) {
            int s, d;
            if (f64) { s = ei[2 * e]; d = ei[2 * E + 2 * e]; }
            else     { s = ei[e];     d = ei[E + e]; }
            wv[q] = ew[e];
            bv[q] = d >> 9;
            loc[q] = atomicAdd(&lcnt[bv[q]], 1);
            sv[q] = s | ((d & 511) << 17);
        } else bv[q] = -1;
    }
    __syncthreads();
    if (t < NB && lcnt[t] > 0)
        lbase[t] = atomicAdd(&pcur[(slot * NB + t) * PST], lcnt[t]);
    __syncthreads();
#pragma unroll
    for (int q = 0; q < 4; ++q) {
        if (bv[q] < 0) continue;
        int pos = lbase[bv[q]] + loc[q];
        if (pos >= CAPP) continue;  // mean 1024 + 8 sigma headroom
        int2 rec;
        rec.x = sv[q];
        rec.y = __float_as_int(wv[q]);
        part[(size_t)(slot * NB + bv[q]) * CAPP + pos] = rec;
    }
}

// ---------------- bucket-base scan (1 block; NB <= 256) ----------------
__global__ void k_bscan(const int* __restrict__ pcur, int* __restrict__ bbase, int NB) {
    __shared__ int lds[256];
    int t = threadIdx.x;
    int tot = 0;
    if (t < NB)
        for (int s = 0; s < 8; ++s) tot += min(pcur[(s * NB + t) * PST], CAPP);
    lds[t] = tot;
    __syncthreads();
    for (int off = 1; off < 256; off <<= 1) {
        int v = (t >= off) ? lds[t - off] : 0;
        __syncthreads();
        lds[t] += v;
        __syncthreads();
    }
    if (t < NB) bbase[t] = lds[t] - tot;  // exclusive
}

// ---------------- pass 2a: per-bucket histogram -> rowptr/rowend/dinv ----------------
__global__ __launch_bounds__(256) void k_bstats(const int2* __restrict__ part,
        const int* __restrict__ pcur, const int* __restrict__ bbase,
        int* __restrict__ rowptr, int* __restrict__ rowend, float* __restrict__ dinv,
        int N, int NB) {
    __shared__ int cnt[512];
    __shared__ float deg[512];
    __shared__ int scn[512];
    int b = blockIdx.x;
    int t = threadIdx.x;
    cnt[t] = 0; cnt[t + 256] = 0;
    deg[t] = 0.f; deg[t + 256] = 0.f;
    __syncthreads();
    for (int slot = 0; slot < 8; ++slot) {
        int n = min(pcur[(slot * NB + b) * PST], CAPP);
        const int2* cell = part + (size_t)(slot * NB + b) * CAPP;
        for (int i = t; i < n; i += 256) {
            int2 r = cell[i];
            int dl = (unsigned)r.x >> 17;
            atomicAdd(&cnt[dl], 1);
            atomicAdd(&deg[dl], __int_as_float(r.y));
        }
    }
    __syncthreads();
    scn[t] = cnt[t]; scn[t + 256] = cnt[t + 256];
    __syncthreads();
    for (int off = 1; off < 512; off <<= 1) {
        int v0 = (t >= off) ? scn[t - off] : 0;
        int i1 = t + 256;
        int v1 = (i1 >= off) ? scn[i1 - off] : 0;
        __syncthreads();
        scn[t] += v0; scn[i1] += v1;
        __syncthreads();
    }
    int base = bbase[b];
    for (int l = t; l < 512; l += 256) {
        int node = (b << 9) + l;
        if (node < N) {
            int rp = base + scn[l] - cnt[l];
            rowptr[node] = rp;
            rowend[node] = rp + cnt[l];
            dinv[node] = rsqrtf(deg[l] + 1.0f);
        }
    }
}

// ---------------- pass 2b: per-bucket scatter into final CSR {src, norm} ----------------
__global__ __launch_bounds__(256) void k_bsort(const int2* __restrict__ part,
        const int* __restrict__ pcur, const int* __restrict__ rowptr,
        const float* __restrict__ dinvArr, int2* __restrict__ ecsr, int N, int NB) {
    __shared__ int lcur[512];
    __shared__ float ldinv[512];
    int b = blockIdx.x;
    int t = threadIdx.x;
    for (int l = t; l < 512; l += 256) {
        int node = (b << 9) + l;
        lcur[l] = (node < N) ? rowptr[node] : 0;
        ldinv[l] = (node < N) ? dinvArr[node] : 0.f;
    }
    __syncthreads();
    for (int slot = 0; slot < 8; ++slot) {
        int n = min(pcur[(slot * NB + b) * PST], CAPP);
        const int2* cell = part + (size_t)(slot * NB + b) * CAPP;
        for (int i = t; i < n; i += 256) {
            int2 r = cell[i];
            int dl = (unsigned)r.x >> 17;
            int s = r.x & 0x1FFFF;
            float w = __int_as_float(r.y);
            int pos = atomicAdd(&lcur[dl], 1);
            int2 o;
            o.x = s;
            o.y = __float_as_int(dinvArr[s] * w * ldinv[dl]);
            ecsr[pos] = o;
        }
    }
}

// ---------------- hybrid MFMA GEMM: B staged in LDS per 128-K chunk, A direct ----------------
// MODE 0: K=64  A=agg0 bf16; out bf16 + bias eb (b1); fused BN stats -> stats
// MODE 1: K=128 A=h1c bf16 + BN(stats,g,be)+ReLU in-reg; out bf16
// MODE 2: K=384 virtual (BN2ReLU(h2c) | dist-feat | degf-feat); out f32 + bias eb (bm)
template <int K, int MODE>
__global__ __launch_bounds__(256) void k_gemm(
        const unsigned short* __restrict__ A, const short* __restrict__ Bt,
        float* __restrict__ stats, const float* __restrict__ g,
        const float* __restrict__ be, const float* __restrict__ dist,
        const float* __restrict__ degf, const float* __restrict__ Wd,
        const float* __restrict__ bd, const float* __restrict__ Wg,
        const float* __restrict__ bg, const float* __restrict__ eb,
        void* __restrict__ out, int N, float invN) {
    constexpr int CH = (K < 128) ? K : 128;
    __shared__ short Bs[128][CH + 8];
    __shared__ float sc[128], sh[128];
    __shared__ float st0[128], st1[128];
    const int t = threadIdx.x;
    const int lane = t & 63;
    const int wave = t >> 6;
    const int rl = lane & 15;
    const int kg = lane >> 4;
    const int r0 = blockIdx.x * 128;

    if (MODE >= 1) {
        if (t < 128) {
            float mean = stats[t] * invN;
            float var = stats[128 + t] * invN - mean * mean;
            float scale = g[t] * rsqrtf(var + BN_EPS);
            sc[t] = scale;
            sh[t] = be[t] - mean * scale;
        }
    }
    if (MODE == 0) {
        if (t < 128) { st0[t] = 0.f; st1[t] = 0.f; }
    }

    f32x4 acc[2][8];
#pragma unroll
    for (int m = 0; m < 2; ++m)
#pragma unroll
        for (int n = 0; n < 8; ++n) acc[m][n] = (f32x4){0.f, 0.f, 0.f, 0.f};

    const int AST = (MODE == 0) ? 64 : 128;
    const int rowbase = r0 + wave * 32 + rl;

    for (int kc = 0; kc < K; kc += CH) {
        if (kc > 0) __syncthreads();
        {
            int c = t >> 1;
            int hb = (t & 1) * (CH / 2);
            const short* wrow = Bt + (size_t)c * K + kc + hb;
#pragma unroll
            for (int q = 0; q < CH / 16; ++q)
                *(int4*)&Bs[c][hb + q * 8] = ((const int4*)wrow)[q];
        }
        __syncthreads();
#pragma unroll
        for (int kt0 = 0; kt0 < CH; kt0 += 32) {
            const int kt = kc + kt0;
            const int k0 = kt + kg * 8;
            const int kl0 = kt0 + kg * 8;
            bf16x8 a[2];
#pragma unroll
            for (int m = 0; m < 2; ++m) {
                const int row = rowbase + m * 16;
                union { int4 q; unsigned short s[8]; } u;
                if (MODE == 2 && kt >= 128) {
                    if (row < N) {
                        const float* Wv; const float* bv; float sx; int cb;
                        if (kt >= 256) { Wv = Wg; bv = bg; sx = degf[row]; cb = k0 - 256; }
                        else           { Wv = Wd; bv = bd; sx = dist[row]; cb = k0 - 128; }
#pragma unroll
                        for (int j = 0; j < 8; ++j)
                            u.s[j] = (unsigned short)f2b(fmaxf(0.f, sx * Wv[cb + j] + bv[cb + j]));
                    } else u.q = (int4){0, 0, 0, 0};
                } else if (MODE == 0) {
                    u.q = (row < N) ? *(const int4*)(A + (size_t)row * AST + k0)
                                    : (int4){0, 0, 0, 0};
                } else {
                    if (row < N) {
                        union { int4 q; unsigned short s[8]; } raw;
                        raw.q = *(const int4*)(A + (size_t)row * AST + k0);
#pragma unroll
                        for (int j = 0; j < 8; ++j)
                            u.s[j] = (unsigned short)f2b(
                                fmaxf(0.f, bu2f(raw.s[j]) * sc[k0 + j] + sh[k0 + j]));
                    } else u.q = (int4){0, 0, 0, 0};
                }
                a[m] = *reinterpret_cast<bf16x8*>(&u);
            }
#pragma unroll
            for (int n = 0; n < 8; ++n) {
                bf16x8 b = *reinterpret_cast<const bf16x8*>(&Bs[n * 16 + rl][kl0]);
                acc[0][n] = __builtin_amdgcn_mfma_f32_16x16x32_bf16(a[0], b, acc[0][n], 0, 0, 0);
                acc[1][n] = __builtin_amdgcn_mfma_f32_16x16x32_bf16(a[1], b, acc[1][n], 0, 0, 0);
            }
        }
    }

    // epilogue (C/D: col=lane&15, row=(lane>>4)*4+reg; m89-verified)
    const int rbase = r0 + wave * 32 + kg * 4;
#pragma unroll
    for (int n = 0; n < 8; ++n) {
        int col = n * 16 + rl;
        float bias = (MODE != 1) ? eb[col] : 0.f;
        float sl = 0.f, ql = 0.f;
#pragma unroll
        for (int m = 0; m < 2; ++m) {
#pragma unroll
            for (int j = 0; j < 4; ++j) {
                int row = rbase + m * 16 + j;
                if (row < N) {
                    float val = acc[m][n][j] + bias;
                    if (MODE == 2) {
                        ((float*)out)[(size_t)row * 128 + col] = val;
                    } else {
                        ((unsigned short*)out)[(size_t)row * 128 + col] = (unsigned short)f2b(val);
                        if (MODE == 0) { sl += val; ql += val * val; }
                    }
                }
            }
        }
        if (MODE == 0) {
            atomicAdd(&st0[col], sl);
            atomicAdd(&st1[col], ql);
        }
    }
    if (MODE == 0) {
        __syncthreads();
        if (t < 128) {
            atomicAdd(&stats[t], st0[t]);
            atomicAdd(&stats[128 + t], st1[t]);
        }
    }
}

// ---------------- CSR gathers ----------------
__global__ void k_gather64(const unsigned short* __restrict__ xb, const int2* __restrict__ ecsr,
                           const int* __restrict__ rowptr, const int* __restrict__ rowend,
                           const float* __restrict__ dinv, unsigned short* __restrict__ agg0,
                           int N) {
    int node = blockIdx.x * 4 + (threadIdx.x >> 6);
    if (node >= N) return;
    int lane = threadIdx.x & 63;
    int start = rowptr[node], end = rowend[node];
    float di = dinv[node];
    float ax = di * di * bu2f(xb[(size_t)node * 64 + lane]);
    int j = start;
    for (; j + 8 <= end; j += 8) {
        float a0 = 0.f, a1 = 0.f;
#pragma unroll
        for (int u = 0; u < 8; u += 2) {
            int2 ea = ecsr[j + u], eb2 = ecsr[j + u + 1];
            a0 += __int_as_float(ea.y)  * bu2f(xb[(size_t)ea.x  * 64 + lane]);
            a1 += __int_as_float(eb2.y) * bu2f(xb[(size_t)eb2.x * 64 + lane]);
        }
        ax += a0 + a1;
    }
    for (; j < end; ++j) {
        int2 e = ecsr[j];
        ax += __int_as_float(e.y) * bu2f(xb[(size_t)e.x * 64 + lane]);
    }
    agg0[(size_t)node * 64 + lane] = (unsigned short)f2b(ax);
}

__global__ void k_gather128b(const unsigned int* __restrict__ t2, const int2* __restrict__ ecsr,
                             const int* __restrict__ rowptr, const int* __restrict__ rowend,
                             const float* __restrict__ dinv, const float* __restrict__ bias,
                             unsigned int* __restrict__ h2c, int N) {
    int node = blockIdx.x * 4 + (threadIdx.x >> 6);
    if (node >= N) return;
    int lane = threadIdx.x & 63;
    int start = rowptr[node], end = rowend[node];
    float di = dinv[node];
    float sl = di * di;
    unsigned int hv = t2[(size_t)node * 64 + lane];
    float2 bv = ((const float2*)bias)[lane];
    float ax = sl * lo16(hv) + bv.x;
    float ay = sl * hi16(hv) + bv.y;
    int j = start;
    for (; j + 16 <= end; j += 16) {
        int2 e[16]; unsigned int v[16];
#pragma unroll
        for (int u = 0; u < 16; ++u) e[u] = ecsr[j + u];
#pragma unroll
        for (int u = 0; u < 16; ++u) v[u] = t2[(size_t)e[u].x * 64 + lane];
#pragma unroll
        for (int u = 0; u < 16; ++u) {
            float w = __int_as_float(e[u].y);
            ax += w * lo16(v[u]);
            ay += w * hi16(v[u]);
        }
    }
    for (; j + 4 <= end; j += 4) {
        int2 e[4]; unsigned int v[4];
#pragma unroll
        for (int u = 0; u < 4; ++u) e[u] = ecsr[j + u];
#pragma unroll
        for (int u = 0; u < 4; ++u) v[u] = t2[(size_t)e[u].x * 64 + lane];
#pragma unroll
        for (int u = 0; u < 4; ++u) {
            float w = __int_as_float(e[u].y);
            ax += w * lo16(v[u]);
            ay += w * hi16(v[u]);
        }
    }
    for (; j < end; ++j) {
        int2 e = ecsr[j];
        float w = __int_as_float(e.y);
        unsigned int v = t2[(size_t)e.x * 64 + lane];
        ax += w * lo16(v);
        ay += w * hi16(v);
    }
    unsigned int packed = (unsigned int)(unsigned short)f2b(ax) |
                          ((unsigned int)(unsigned short)f2b(ay) << 16);
    h2c[(size_t)node * 64 + lane] = packed;
}

// ---------------- BN2 stats: vectorized partials + final reduce ----------------
__global__ __launch_bounds__(256) void k_bn_partial(const uint4* __restrict__ h,
                                                    float* __restrict__ part, int total4) {
    __shared__ float sm[256];
    sm[threadIdx.x] = 0.f;
    __syncthreads();
    float s[8], q[8];
#pragma unroll
    for (int j = 0; j < 8; ++j) { s[j] = 0.f; q[j] = 0.f; }
    int stride = gridDim.x * 256;
    for (int i = blockIdx.x * 256 + threadIdx.x; i < total4; i += stride) {
        uint4 v = h[i];
        float a;
        a = lo16(v.x); s[0] += a; q[0] += a * a;
        a = hi16(v.x); s[1] += a; q[1] += a * a;
        a = lo16(v.y); s[2] += a; q[2] += a * a;
        a = hi16(v.y); s[3] += a; q[3] += a * a;
        a = lo16(v.z); s[4] += a; q[4] += a * a;
        a = hi16(v.z); s[5] += a; q[5] += a * a;
        a = lo16(v.w); s[6] += a; q[6] += a * a;
        a = hi16(v.w); s[7] += a; q[7] += a * a;
    }
    int c0 = 8 * (threadIdx.x & 15);
#pragma unroll
    for (int j = 0; j < 8; ++j) {
        atomicAdd(&sm[c0 + j], s[j]);
        atomicAdd(&sm[128 + c0 + j], q[j]);
    }
    __syncthreads();
    part[blockIdx.x * 256 + threadIdx.x] = sm[threadIdx.x];
}

__global__ void k_bn_reduce(const float* __restrict__ part, float* __restrict__ stats, int nb) {
    int t = threadIdx.x;
    float acc = 0.f;
#pragma unroll 4
    for (int b = 0; b < nb; ++b) acc += part[b * 256 + t];
    stats[t] = acc;
}

extern "C" void kernel_launch(void* const* d_in, const int* in_sizes, int n_in,
                              void* d_out, int out_size, void* d_ws, size_t ws_size,
                              hipStream_t stream) {
    const float* x    = (const float*)d_in[0];
    const int*   ei   = (const int*)d_in[1];
    const float* ew   = (const float*)d_in[2];
    const float* dist = (const float*)d_in[3];
    const float* degf = (const float*)d_in[4];
    const float* W1   = (const float*)d_in[5];
    const float* b1   = (const float*)d_in[6];
    const float* W2   = (const float*)d_in[7];
    const float* b2   = (const float*)d_in[8];
    const float* g1   = (const float*)d_in[9];
    const float* be1  = (const float*)d_in[10];
    const float* g2   = (const float*)d_in[11];
    const float* be2  = (const float*)d_in[12];
    const float* Wd   = (const float*)d_in[13];
    const float* bd   = (const float*)d_in[14];
    const float* Wg   = (const float*)d_in[15];
    const float* bg   = (const float*)d_in[16];
    const float* Wm   = (const float*)d_in[17];
    const float* bm   = (const float*)d_in[18];

    const int IN = 64;
    const int N = in_sizes[0] / IN;   // 100000
    const int E = in_sizes[1] / 2;    // 1600000
    const int NB = (N + 511) >> 9;    // 196 buckets (<= NBC)

    // ws layout (4B words):
    int*   pcur   = (int*)d_ws;                                      // [8*NBC*PST] (padded cursors)
    float* stats  = (float*)(pcur + 8 * NBC * PST);                  // [512]
    int*   flag   = (int*)(stats + 512);
    int*   bbase  = flag + 32;                                       // [NBC]
    int*   rowptr = bbase + NBC;                                     // [N]
    int*   rowend = rowptr + N;                                      // [N]
    float* dinv   = (float*)(rowend + N);                            // [N]
    int2*  partb  = (int2*)(dinv + N);                               // [8*NBC*CAPP] int2 (21 MB)
    int2*  ecsr   = partb + (size_t)8 * NBC * CAPP;                  // [E] int2
    unsigned int*   h2c  = (unsigned int*)(ecsr + E);                // N*128 bf16
    unsigned short* agg0 = (unsigned short*)(h2c + (size_t)N * 64);  // N*64 bf16
    unsigned short* xb   = agg0 + (size_t)N * 64;                    // N*64 bf16
    short* w1t    = (short*)(xb + (size_t)N * 64);                   // [128][64]
    short* w2t    = w1t + 128 * 64;                                  // [128][128]
    short* wmt    = w2t + 128 * 128;                                 // [128][384]
    float* bnpart = (float*)(wmt + 128 * 384);                       // [512][256]

    // d_out time-share (bf16 staging, overwritten by final f32 GEMM)
    unsigned short* h1c = (unsigned short*)d_out;                    // N*128 bf16
    unsigned int*   t2  = (unsigned int*)d_out + (size_t)N * 64;     // N*128 bf16 pairs

    hipMemsetAsync(pcur, 0, (8 * NBC * PST + 512) * sizeof(int), stream);  // pcur + stats

    const int nchunkP = (E + 1023) / 1024;
    const int nbG  = (N + 3) / 4;
    const int nbPrep = 1 + 288 + (N * 16 + 255) / 256;

    k_prep<<<nbPrep, 256, 0, stream>>>(ei, flag, W1, W2, Wm, w1t, w2t, wmt, x, xb, N * 16);
    k_part<<<nchunkP, 256, 0, stream>>>(ei, ew, flag, pcur, partb, E, NB);
    k_bscan<<<1, 256, 0, stream>>>(pcur, bbase, NB);
    k_bstats<<<NB, 256, 0, stream>>>(partb, pcur, bbase, rowptr, rowend, dinv, N, NB);
    k_bsort<<<NB, 256, 0, stream>>>(partb, pcur, rowptr, dinv, ecsr, N, NB);

    const int nbGe = (N + 127) / 128;
    const int nbP  = 512;
    const float invN = 1.0f / (float)N;

    // layer 1: agg0 = A_hat @ x; h1c = agg0 @ W1 + b1 (stats1 fused in epilogue)
    k_gather64<<<nbG, 256, 0, stream>>>(xb, ecsr, rowptr, rowend, dinv, agg0, N);
    k_gemm<64, 0><<<nbGe, 256, 0, stream>>>(agg0, w1t, stats, nullptr, nullptr, nullptr,
                                            nullptr, nullptr, nullptr, nullptr, nullptr,
                                            b1, h1c, N, invN);

    // layer 2: t2 = BN1ReLU(h1c) @ W2; h2c = A_hat @ t2 + b2; stats2 (two-stage)
    k_gemm<128, 1><<<nbGe, 256, 0, stream>>>(h1c, w2t, stats, g1, be1, nullptr,
                                             nullptr, nullptr, nullptr, nullptr, nullptr,
                                             nullptr, t2, N, invN);
    k_gather128b<<<nbG, 256, 0, stream>>>(t2, ecsr, rowptr, rowend, dinv, b2, h2c, N);
    k_bn_partial<<<nbP, 256, 0, stream>>>((const uint4*)h2c, bnpart, N * 16);
    k_bn_reduce<<<1, 256, 0, stream>>>(bnpart, stats + 256, nbP);

    // final: [BN2ReLU(h2c) | relu(dist*Wd+bd) | relu(degf*Wg+bg)] @ Wm + bm -> d_out f32
    k_gemm<384, 2><<<nbGe, 256, 0, stream>>>((const unsigned short*)h2c, wmt, stats + 256,
                                             g2, be2, dist, degf, Wd, bd, Wg, bg,
                                             bm, d_out, N, invN);
}

// Round 17
// 375.435 us; speedup vs baseline: 1.5222x; 1.0134x over previous
//
#include <hip/hip_runtime.h>
#include <hip/hip_bf16.h>

#define BN_EPS 1e-5f

typedef __attribute__((ext_vector_type(8))) short bf16x8;
typedef __attribute__((ext_vector_type(4))) float f32x4;

__device__ __forceinline__ short f2b(float f) {
    __hip_bfloat16 h = __float2bfloat16(f);
    return *reinterpret_cast<short*>(&h);
}
__device__ __forceinline__ float bu2f(unsigned short u) {
    return __uint_as_float(((unsigned int)u) << 16);
}
__device__ __forceinline__ float lo16(unsigned int v) { return __uint_as_float(v << 16); }
__device__ __forceinline__ float hi16(unsigned int v) { return __uint_as_float(v & 0xffff0000u); }
__device__ __forceinline__ unsigned int pk2(float a, float b) {
    return (unsigned int)(unsigned short)f2b(a) | ((unsigned int)(unsigned short)f2b(b) << 16);
}

#define CAPP 1280     /* records per (slot,bucket) cell: mean 1024 + 8 sigma */
#define NBC  256      /* allocated bucket slots (N <= 131072) */
#define PST  16       /* cursor padding: one cache line per cursor */

// ---------------- fused prep: flag probe | weight transpose | x->bf16 ----------------
__global__ void k_prep(const int* __restrict__ ei, int* __restrict__ flag,
                       const float* __restrict__ W1, const float* __restrict__ W2,
                       const float* __restrict__ Wm, short* __restrict__ w1t,
                       short* __restrict__ w2t, short* __restrict__ wmt,
                       const float* __restrict__ x, unsigned short* __restrict__ xb,
                       int total4x) {
    int gb = blockIdx.x;
    if (gb == 0) {
        __shared__ int any;
        if (threadIdx.x == 0) any = 0;
        __syncthreads();
        if (ei[2 * threadIdx.x + 1] != 0) atomicOr(&any, 1);
        __syncthreads();
        if (threadIdx.x == 0) *flag = (any == 0);  // all-high-words-zero => int64
    } else if (gb <= 288) {
        int idx = (gb - 1) * 256 + threadIdx.x;
        if (idx < 128 * 64) {
            int c = idx >> 6, k = idx & 63;
            w1t[idx] = f2b(W1[k * 128 + c]);
        } else if (idx < 128 * 64 + 128 * 128) {
            int i = idx - 128 * 64; int c = i >> 7, k = i & 127;
            w2t[i] = f2b(W2[k * 128 + c]);
        } else if (idx < 128 * 64 + 128 * 128 + 128 * 384) {
            int i = idx - (128 * 64 + 128 * 128); int c = i / 384, k = i % 384;
            wmt[i] = f2b(Wm[k * 128 + c]);
        }
    } else {
        int i = (gb - 289) * 256 + threadIdx.x;
        if (i >= total4x) return;
        float4 v = ((const float4*)x)[i];
        ushort4 o;
        o.x = (unsigned short)f2b(v.x);
        o.y = (unsigned short)f2b(v.y);
        o.z = (unsigned short)f2b(v.z);
        o.w = (unsigned short)f2b(v.w);
        ((ushort4*)xb)[i] = o;
    }
}

// ---------------- pass 1: partition edges into (slot, dst>>9) cells ----------------
__global__ __launch_bounds__(256) void k_part(const int* __restrict__ ei,
        const float* __restrict__ ew, const int* __restrict__ flag,
        int* __restrict__ pcur, int2* __restrict__ part, int E, int NB) {
    __shared__ int lcnt[NBC];
    __shared__ int lbase[NBC];
    int t = threadIdx.x;
    int slot = blockIdx.x & 7;
    for (int i = t; i < NBC; i += 256) lcnt[i] = 0;
    __syncthreads();
    int e0 = blockIdx.x * 1024;
    bool f64 = (*flag != 0);
    int sv[4], bv[4], loc[4]; float wv[4];
#pragma unroll
    for (int q = 0; q < 4; ++q) {
        int e = e0 + q * 256 + t;
        if (e < E) {
            int s, d;
            if (f64) { s = ei[2 * e]; d = ei[2 * E + 2 * e]; }
            else     { s = ei[e];     d = ei[E + e]; }
            wv[q] = ew[e];
            bv[q] = d >> 9;
            loc[q] = atomicAdd(&lcnt[bv[q]], 1);
            sv[q] = s | ((d & 511) << 17);
        } else bv[q] = -1;
    }
    __syncthreads();
    if (t < NB && lcnt[t] > 0)
        lbase[t] = atomicAdd(&pcur[(slot * NB + t) * PST], lcnt[t]);
    __syncthreads();
#pragma unroll
    for (int q = 0; q < 4; ++q) {
        if (bv[q] < 0) continue;
        int pos = lbase[bv[q]] + loc[q];
        if (pos >= CAPP) continue;
        int2 rec;
        rec.x = sv[q];
        rec.y = __float_as_int(wv[q]);
        part[(size_t)(slot * NB + bv[q]) * CAPP + pos] = rec;
    }
}

// ---------------- bucket-base scan (1 block; NB <= 256) ----------------
__global__ void k_bscan(const int* __restrict__ pcur, int* __restrict__ bbase, int NB) {
    __shared__ int lds[256];
    int t = threadIdx.x;
    int tot = 0;
    if (t < NB)
        for (int s = 0; s < 8; ++s) tot += min(pcur[(s * NB + t) * PST], CAPP);
    lds[t] = tot;
    __syncthreads();
    for (int off = 1; off < 256; off <<= 1) {
        int v = (t >= off) ? lds[t - off] : 0;
        __syncthreads();
        lds[t] += v;
        __syncthreads();
    }
    if (t < NB) bbase[t] = lds[t] - tot;  // exclusive
}

// ---------------- pass 2a: per-bucket histogram -> rowptr/rowend/dinv ----------------
__global__ __launch_bounds__(256) void k_bstats(const int2* __restrict__ part,
        const int* __restrict__ pcur, const int* __restrict__ bbase,
        int* __restrict__ rowptr, int* __restrict__ rowend, float* __restrict__ dinv,
        int N, int NB) {
    __shared__ int cnt[512];
    __shared__ float deg[512];
    __shared__ int scn[512];
    int b = blockIdx.x;
    int t = threadIdx.x;
    cnt[t] = 0; cnt[t + 256] = 0;
    deg[t] = 0.f; deg[t + 256] = 0.f;
    __syncthreads();
    for (int slot = 0; slot < 8; ++slot) {
        int n = min(pcur[(slot * NB + b) * PST], CAPP);
        const int2* cell = part + (size_t)(slot * NB + b) * CAPP;
        for (int i = t; i < n; i += 256) {
            int2 r = cell[i];
            int dl = (unsigned)r.x >> 17;
            atomicAdd(&cnt[dl], 1);
            atomicAdd(&deg[dl], __int_as_float(r.y));
        }
    }
    __syncthreads();
    scn[t] = cnt[t]; scn[t + 256] = cnt[t + 256];
    __syncthreads();
    for (int off = 1; off < 512; off <<= 1) {
        int v0 = (t >= off) ? scn[t - off] : 0;
        int i1 = t + 256;
        int v1 = (i1 >= off) ? scn[i1 - off] : 0;
        __syncthreads();
        scn[t] += v0; scn[i1] += v1;
        __syncthreads();
    }
    int base = bbase[b];
    for (int l = t; l < 512; l += 256) {
        int node = (b << 9) + l;
        if (node < N) {
            int rp = base + scn[l] - cnt[l];
            rowptr[node] = rp;
            rowend[node] = rp + cnt[l];
            dinv[node] = rsqrtf(deg[l] + 1.0f);
        }
    }
}

// ---------------- pass 2b: per-bucket scatter into final CSR {src, norm} ----------------
__global__ __launch_bounds__(256) void k_bsort(const int2* __restrict__ part,
        const int* __restrict__ pcur, const int* __restrict__ rowptr,
        const float* __restrict__ dinvArr, int2* __restrict__ ecsr, int N, int NB) {
    __shared__ int lcur[512];
    __shared__ float ldinv[512];
    int b = blockIdx.x;
    int t = threadIdx.x;
    for (int l = t; l < 512; l += 256) {
        int node = (b << 9) + l;
        lcur[l] = (node < N) ? rowptr[node] : 0;
        ldinv[l] = (node < N) ? dinvArr[node] : 0.f;
    }
    __syncthreads();
    for (int slot = 0; slot < 8; ++slot) {
        int n = min(pcur[(slot * NB + b) * PST], CAPP);
        const int2* cell = part + (size_t)(slot * NB + b) * CAPP;
        for (int i = t; i < n; i += 256) {
            int2 r = cell[i];
            int dl = (unsigned)r.x >> 17;
            int s = r.x & 0x1FFFF;
            float w = __int_as_float(r.y);
            int pos = atomicAdd(&lcur[dl], 1);
            int2 o;
            o.x = s;
            o.y = __float_as_int(dinvArr[s] * w * ldinv[dl]);
            ecsr[pos] = o;
        }
    }
}

// ---------------- hybrid MFMA GEMM: B staged in LDS per 128-K chunk, A direct ----------------
// MODE 0: K=64  A=agg0 bf16; out bf16 + bias eb (b1); fused BN stats -> stats
// MODE 1: K=128 A=h1c bf16 + BN(stats,g,be)+ReLU in-reg; out bf16
// MODE 2: K=384 virtual (BN2ReLU(h2c) | dist-feat | degf-feat); out f32 + bias eb (bm)
template <int K, int MODE>
__global__ __launch_bounds__(256) void k_gemm(
        const unsigned short* __restrict__ A, const short* __restrict__ Bt,
        float* __restrict__ stats, const float* __restrict__ g,
        const float* __restrict__ be, const float* __restrict__ dist,
        const float* __restrict__ degf, const float* __restrict__ Wd,
        const float* __restrict__ bd, const float* __restrict__ Wg,
        const float* __restrict__ bg, const float* __restrict__ eb,
        void* __restrict__ out, int N, float invN) {
    constexpr int CH = (K < 128) ? K : 128;
    __shared__ short Bs[128][CH + 8];
    __shared__ float sc[128], sh[128];
    __shared__ float st0[128], st1[128];
    const int t = threadIdx.x;
    const int lane = t & 63;
    const int wave = t >> 6;
    const int rl = lane & 15;
    const int kg = lane >> 4;
    const int r0 = blockIdx.x * 128;

    if (MODE >= 1) {
        if (t < 128) {
            float mean = stats[t] * invN;
            float var = stats[128 + t] * invN - mean * mean;
            float scale = g[t] * rsqrtf(var + BN_EPS);
            sc[t] = scale;
            sh[t] = be[t] - mean * scale;
        }
    }
    if (MODE == 0) {
        if (t < 128) { st0[t] = 0.f; st1[t] = 0.f; }
    }

    f32x4 acc[2][8];
#pragma unroll
    for (int m = 0; m < 2; ++m)
#pragma unroll
        for (int n = 0; n < 8; ++n) acc[m][n] = (f32x4){0.f, 0.f, 0.f, 0.f};

    const int AST = (MODE == 0) ? 64 : 128;
    const int rowbase = r0 + wave * 32 + rl;

    for (int kc = 0; kc < K; kc += CH) {
        if (kc > 0) __syncthreads();
        {
            int c = t >> 1;
            int hb = (t & 1) * (CH / 2);
            const short* wrow = Bt + (size_t)c * K + kc + hb;
#pragma unroll
            for (int q = 0; q < CH / 16; ++q)
                *(int4*)&Bs[c][hb + q * 8] = ((const int4*)wrow)[q];
        }
        __syncthreads();
#pragma unroll
        for (int kt0 = 0; kt0 < CH; kt0 += 32) {
            const int kt = kc + kt0;
            const int k0 = kt + kg * 8;
            const int kl0 = kt0 + kg * 8;
            bf16x8 a[2];
#pragma unroll
            for (int m = 0; m < 2; ++m) {
                const int row = rowbase + m * 16;
                union { int4 q; unsigned short s[8]; } u;
                if (MODE == 2 && kt >= 128) {
                    if (row < N) {
                        const float* Wv; const float* bv; float sx; int cb;
                        if (kt >= 256) { Wv = Wg; bv = bg; sx = degf[row]; cb = k0 - 256; }
                        else           { Wv = Wd; bv = bd; sx = dist[row]; cb = k0 - 128; }
#pragma unroll
                        for (int j = 0; j < 8; ++j)
                            u.s[j] = (unsigned short)f2b(fmaxf(0.f, sx * Wv[cb + j] + bv[cb + j]));
                    } else u.q = (int4){0, 0, 0, 0};
                } else if (MODE == 0) {
                    u.q = (row < N) ? *(const int4*)(A + (size_t)row * AST + k0)
                                    : (int4){0, 0, 0, 0};
                } else {
                    if (row < N) {
                        union { int4 q; unsigned short s[8]; } raw;
                        raw.q = *(const int4*)(A + (size_t)row * AST + k0);
#pragma unroll
                        for (int j = 0; j < 8; ++j)
                            u.s[j] = (unsigned short)f2b(
                                fmaxf(0.f, bu2f(raw.s[j]) * sc[k0 + j] + sh[k0 + j]));
                    } else u.q = (int4){0, 0, 0, 0};
                }
                a[m] = *reinterpret_cast<bf16x8*>(&u);
            }
#pragma unroll
            for (int n = 0; n < 8; ++n) {
                bf16x8 b = *reinterpret_cast<const bf16x8*>(&Bs[n * 16 + rl][kl0]);
                acc[0][n] = __builtin_amdgcn_mfma_f32_16x16x32_bf16(a[0], b, acc[0][n], 0, 0, 0);
                acc[1][n] = __builtin_amdgcn_mfma_f32_16x16x32_bf16(a[1], b, acc[1][n], 0, 0, 0);
            }
        }
    }

    // epilogue (C/D: col=lane&15, row=(lane>>4)*4+reg; m89-verified)
    const int rbase = r0 + wave * 32 + kg * 4;
#pragma unroll
    for (int n = 0; n < 8; ++n) {
        int col = n * 16 + rl;
        float bias = (MODE != 1) ? eb[col] : 0.f;
        float sl = 0.f, ql = 0.f;
#pragma unroll
        for (int m = 0; m < 2; ++m) {
#pragma unroll
            for (int j = 0; j < 4; ++j) {
                int row = rbase + m * 16 + j;
                if (row < N) {
                    float val = acc[m][n][j] + bias;
                    if (MODE == 2) {
                        ((float*)out)[(size_t)row * 128 + col] = val;
                    } else {
                        ((unsigned short*)out)[(size_t)row * 128 + col] = (unsigned short)f2b(val);
                        if (MODE == 0) { sl += val; ql += val * val; }
                    }
                }
            }
        }
        if (MODE == 0) {
            atomicAdd(&st0[col], sl);
            atomicAdd(&st1[col], ql);
        }
    }
    if (MODE == 0) {
        __syncthreads();
        if (t < 128) {
            atomicAdd(&stats[t], st0[t]);
            atomicAdd(&stats[128 + t], st1[t]);
        }
    }
}

// ---------------- CSR gathers: half-wave edge pairing ----------------
// Each half-wave (32 lanes) owns one edge; lane loads 2 channels (uint).
// Wave processes 2 edges/iter, unroll 4 -> 8 edges in flight, half the
// instruction count of the 2B/lane version. shfl_xor(32) merges halves.
__global__ void k_gather64(const unsigned short* __restrict__ xb, const int2* __restrict__ ecsr,
                           const int* __restrict__ rowptr, const int* __restrict__ rowend,
                           const float* __restrict__ dinv, unsigned short* __restrict__ agg0,
                           int N) {
    int node = blockIdx.x * 4 + (threadIdx.x >> 6);
    if (node >= N) return;
    int lane = threadIdx.x & 63;
    int half = lane >> 5;
    int cl = lane & 31;
    const unsigned int* xt = (const unsigned int*)xb;   // uint = 2 channels
    int start = rowptr[node], end = rowend[node];
    float ax = 0.f, ay = 0.f;
    int j = start + half;
    for (; j + 6 < end; j += 8) {
        int2 e0 = ecsr[j], e1 = ecsr[j + 2], e2 = ecsr[j + 4], e3 = ecsr[j + 6];
        unsigned int v0 = xt[(size_t)e0.x * 32 + cl];
        unsigned int v1 = xt[(size_t)e1.x * 32 + cl];
        unsigned int v2 = xt[(size_t)e2.x * 32 + cl];
        unsigned int v3 = xt[(size_t)e3.x * 32 + cl];
        float w0 = __int_as_float(e0.y), w1 = __int_as_float(e1.y);
        float w2 = __int_as_float(e2.y), w3 = __int_as_float(e3.y);
        ax += w0 * lo16(v0) + w1 * lo16(v1) + w2 * lo16(v2) + w3 * lo16(v3);
        ay += w0 * hi16(v0) + w1 * hi16(v1) + w2 * hi16(v2) + w3 * hi16(v3);
    }
    for (; j < end; j += 2) {
        int2 e = ecsr[j];
        unsigned int v = xt[(size_t)e.x * 32 + cl];
        float w = __int_as_float(e.y);
        ax += w * lo16(v);
        ay += w * hi16(v);
    }
    ax += __shfl_xor(ax, 32);
    ay += __shfl_xor(ay, 32);
    if (half == 0) {
        float di = dinv[node];
        unsigned int hv = xt[(size_t)node * 32 + cl];
        ax += di * di * lo16(hv);
        ay += di * di * hi16(hv);
        ((unsigned int*)agg0)[(size_t)node * 32 + cl] = pk2(ax, ay);
    }
}

// lane loads uint2 = 4 channels; half-wave per edge; 2 edges/iter.
__global__ void k_gather128b(const uint2* __restrict__ t2, const int2* __restrict__ ecsr,
                             const int* __restrict__ rowptr, const int* __restrict__ rowend,
                             const float* __restrict__ dinv, const float* __restrict__ bias,
                             uint2* __restrict__ h2c, int N) {
    int node = blockIdx.x * 4 + (threadIdx.x >> 6);
    if (node >= N) return;
    int lane = threadIdx.x & 63;
    int half = lane >> 5;
    int cl = lane & 31;
    int start = rowptr[node], end = rowend[node];
    float a0 = 0.f, a1 = 0.f, a2 = 0.f, a3 = 0.f;
    int j = start + half;
    for (; j + 6 < end; j += 8) {
        int2 e0 = ecsr[j], e1 = ecsr[j + 2], e2 = ecsr[j + 4], e3 = ecsr[j + 6];
        uint2 v0 = t2[(size_t)e0.x * 32 + cl];
        uint2 v1 = t2[(size_t)e1.x * 32 + cl];
        uint2 v2 = t2[(size_t)e2.x * 32 + cl];
        uint2 v3 = t2[(size_t)e3.x * 32 + cl];
        float w0 = __int_as_float(e0.y), w1 = __int_as_float(e1.y);
        float w2 = __int_as_float(e2.y), w3 = __int_as_float(e3.y);
        a0 += w0 * lo16(v0.x) + w1 * lo16(v1.x) + w2 * lo16(v2.x) + w3 * lo16(v3.x);
        a1 += w0 * hi16(v0.x) + w1 * hi16(v1.x) + w2 * hi16(v2.x) + w3 * hi16(v3.x);
        a2 += w0 * lo16(v0.y) + w1 * lo16(v1.y) + w2 * lo16(v2.y) + w3 * lo16(v3.y);
        a3 += w0 * hi16(v0.y) + w1 * hi16(v1.y) + w2 * hi16(v2.y) + w3 * hi16(v3.y);
    }
    for (; j < end; j += 2) {
        int2 e = ecsr[j];
        uint2 v = t2[(size_t)e.x * 32 + cl];
        float w = __int_as_float(e.y);
        a0 += w * lo16(v.x);
        a1 += w * hi16(v.x);
        a2 += w * lo16(v.y);
        a3 += w * hi16(v.y);
    }
    a0 += __shfl_xor(a0, 32);
    a1 += __shfl_xor(a1, 32);
    a2 += __shfl_xor(a2, 32);
    a3 += __shfl_xor(a3, 32);
    if (half == 0) {
        float di = dinv[node];
        float sl = di * di;
        uint2 hv = t2[(size_t)node * 32 + cl];
        float4 bv = ((const float4*)bias)[cl];
        a0 += sl * lo16(hv.x) + bv.x;
        a1 += sl * hi16(hv.x) + bv.y;
        a2 += sl * lo16(hv.y) + bv.z;
        a3 += sl * hi16(hv.y) + bv.w;
        uint2 o;
        o.x = pk2(a0, a1);
        o.y = pk2(a2, a3);
        h2c[(size_t)node * 32 + cl] = o;
    }
}

// ---------------- BN2 stats: vectorized partials + final reduce ----------------
__global__ __launch_bounds__(256) void k_bn_partial(const uint4* __restrict__ h,
                                                    float* __restrict__ part, int total4) {
    __shared__ float sm[256];
    sm[threadIdx.x] = 0.f;
    __syncthreads();
    float s[8], q[8];
#pragma unroll
    for (int j = 0; j < 8; ++j) { s[j] = 0.f; q[j] = 0.f; }
    int stride = gridDim.x * 256;
    for (int i = blockIdx.x * 256 + threadIdx.x; i < total4; i += stride) {
        uint4 v = h[i];
        float a;
        a = lo16(v.x); s[0] += a; q[0] += a * a;
        a = hi16(v.x); s[1] += a; q[1] += a * a;
        a = lo16(v.y); s[2] += a; q[2] += a * a;
        a = hi16(v.y); s[3] += a; q[3] += a * a;
        a = lo16(v.z); s[4] += a; q[4] += a * a;
        a = hi16(v.z); s[5] += a; q[5] += a * a;
        a = lo16(v.w); s[6] += a; q[6] += a * a;
        a = hi16(v.w); s[7] += a; q[7] += a * a;
    }
    int c0 = 8 * (threadIdx.x & 15);
#pragma unroll
    for (int j = 0; j < 8; ++j) {
        atomicAdd(&sm[c0 + j], s[j]);
        atomicAdd(&sm[128 + c0 + j], q[j]);
    }
    __syncthreads();
    part[blockIdx.x * 256 + threadIdx.x] = sm[threadIdx.x];
}

__global__ void k_bn_reduce(const float* __restrict__ part, float* __restrict__ stats, int nb) {
    int t = threadIdx.x;
    float acc = 0.f;
#pragma unroll 4
    for (int b = 0; b < nb; ++b) acc += part[b * 256 + t];
    stats[t] = acc;
}

extern "C" void kernel_launch(void* const* d_in, const int* in_sizes, int n_in,
                              void* d_out, int out_size, void* d_ws, size_t ws_size,
                              hipStream_t stream) {
    const float* x    = (const float*)d_in[0];
    const int*   ei   = (const int*)d_in[1];
    const float* ew   = (const float*)d_in[2];
    const float* dist = (const float*)d_in[3];
    const float* degf = (const float*)d_in[4];
    const float* W1   = (const float*)d_in[5];
    const float* b1   = (const float*)d_in[6];
    const float* W2   = (const float*)d_in[7];
    const float* b2   = (const float*)d_in[8];
    const float* g1   = (const float*)d_in[9];
    const float* be1  = (const float*)d_in[10];
    const float* g2   = (const float*)d_in[11];
    const float* be2  = (const float*)d_in[12];
    const float* Wd   = (const float*)d_in[13];
    const float* bd   = (const float*)d_in[14];
    const float* Wg   = (const float*)d_in[15];
    const float* bg   = (const float*)d_in[16];
    const float* Wm   = (const float*)d_in[17];
    const float* bm   = (const float*)d_in[18];

    const int IN = 64;
    const int N = in_sizes[0] / IN;   // 100000
    const int E = in_sizes[1] / 2;    // 1600000
    const int NB = (N + 511) >> 9;    // 196 buckets (<= NBC)

    // ws layout (4B words):
    int*   pcur   = (int*)d_ws;                                      // [8*NBC*PST]
    float* stats  = (float*)(pcur + 8 * NBC * PST);                  // [512]
    int*   flag   = (int*)(stats + 512);
    int*   bbase  = flag + 32;                                       // [NBC]
    int*   rowptr = bbase + NBC;                                     // [N]
    int*   rowend = rowptr + N;                                      // [N]
    float* dinv   = (float*)(rowend + N);                            // [N]
    int2*  partb  = (int2*)(dinv + N);                               // [8*NBC*CAPP] int2
    int2*  ecsr   = partb + (size_t)8 * NBC * CAPP;                  // [E] int2
    unsigned int*   h2c  = (unsigned int*)(ecsr + E);                // N*128 bf16
    unsigned short* agg0 = (unsigned short*)(h2c + (size_t)N * 64);  // N*64 bf16
    unsigned short* xb   = agg0 + (size_t)N * 64;                    // N*64 bf16
    short* w1t    = (short*)(xb + (size_t)N * 64);                   // [128][64]
    short* w2t    = w1t + 128 * 64;                                  // [128][128]
    short* wmt    = w2t + 128 * 128;                                 // [128][384]
    float* bnpart = (float*)(wmt + 128 * 384);                       // [512][256]

    // d_out time-share (bf16 staging, overwritten by final f32 GEMM)
    unsigned short* h1c = (unsigned short*)d_out;                    // N*128 bf16
    unsigned int*   t2  = (unsigned int*)d_out + (size_t)N * 64;     // N*128 bf16 pairs

    hipMemsetAsync(pcur, 0, (8 * NBC * PST + 512) * sizeof(int), stream);

    const int nchunkP = (E + 1023) / 1024;
    const int nbG  = (N + 3) / 4;
    const int nbPrep = 1 + 288 + (N * 16 + 255) / 256;

    k_prep<<<nbPrep, 256, 0, stream>>>(ei, flag, W1, W2, Wm, w1t, w2t, wmt, x, xb, N * 16);
    k_part<<<nchunkP, 256, 0, stream>>>(ei, ew, flag, pcur, partb, E, NB);
    k_bscan<<<1, 256, 0, stream>>>(pcur, bbase, NB);
    k_bstats<<<NB, 256, 0, stream>>>(partb, pcur, bbase, rowptr, rowend, dinv, N, NB);
    k_bsort<<<NB, 256, 0, stream>>>(partb, pcur, rowptr, dinv, ecsr, N, NB);

    const int nbGe = (N + 127) / 128;
    const int nbP  = 512;
    const float invN = 1.0f / (float)N;

    // layer 1: agg0 = A_hat @ x; h1c = agg0 @ W1 + b1 (stats1 fused in epilogue)
    k_gather64<<<nbG, 256, 0, stream>>>(xb, ecsr, rowptr, rowend, dinv, agg0, N);
    k_gemm<64, 0><<<nbGe, 256, 0, stream>>>(agg0, w1t, stats, nullptr, nullptr, nullptr,
                                            nullptr, nullptr, nullptr, nullptr, nullptr,
                                            b1, h1c, N, invN);

    // layer 2: t2 = BN1ReLU(h1c) @ W2; h2c = A_hat @ t2 + b2; stats2 (two-stage)
    k_gemm<128, 1><<<nbGe, 256, 0, stream>>>(h1c, w2t, stats, g1, be1, nullptr,
                                             nullptr, nullptr, nullptr, nullptr, nullptr,
                                             nullptr, t2, N, invN);
    k_gather128b<<<nbG, 256, 0, stream>>>((const uint2*)t2, ecsr, rowptr, rowend, dinv,
                                          b2, (uint2*)h2c, N);
    k_bn_partial<<<nbP, 256, 0, stream>>>((const uint4*)h2c, bnpart, N * 16);
    k_bn_reduce<<<1, 256, 0, stream>>>(bnpart, stats + 256, nbP);

    // final: [BN2ReLU(h2c) | relu(dist*Wd+bd) | relu(degf*Wg+bg)] @ Wm + bm -> d_out f32
    k_gemm<384, 2><<<nbGe, 256, 0, stream>>>((const unsigned short*)h2c, wmt, stats + 256,
                                             g2, be2, dist, degf, Wd, bd, Wg, bg,
                                             bm, d_out, N, invN);
}

// Round 18
// 361.675 us; speedup vs baseline: 1.5801x; 1.0380x over previous
//
#include <hip/hip_runtime.h>
#include <hip/hip_bf16.h>

#define BN_EPS 1e-5f

typedef __attribute__((ext_vector_type(8))) short bf16x8;
typedef __attribute__((ext_vector_type(4))) float f32x4;

__device__ __forceinline__ short f2b(float f) {
    __hip_bfloat16 h = __float2bfloat16(f);
    return *reinterpret_cast<short*>(&h);
}
__device__ __forceinline__ float bu2f(unsigned short u) {
    return __uint_as_float(((unsigned int)u) << 16);
}
__device__ __forceinline__ float lo16(unsigned int v) { return __uint_as_float(v << 16); }
__device__ __forceinline__ float hi16(unsigned int v) { return __uint_as_float(v & 0xffff0000u); }
__device__ __forceinline__ unsigned int pk2(float a, float b) {
    return (unsigned int)(unsigned short)f2b(a) | ((unsigned int)(unsigned short)f2b(b) << 16);
}

#define CAPP 1280     /* records per (slot,bucket) cell: mean 1024 + 8 sigma */
#define NBC  256      /* allocated bucket slots (N <= 131072) */
#define PST  16       /* cursor padding: one cache line per cursor */

// ---------------- fused prep: flag probe | weight transpose | x->bf16 ----------------
__global__ void k_prep(const int* __restrict__ ei, int* __restrict__ flag,
                       const float* __restrict__ W1, const float* __restrict__ W2,
                       const float* __restrict__ Wm, short* __restrict__ w1t,
                       short* __restrict__ w2t, short* __restrict__ wmt,
                       const float* __restrict__ x, unsigned short* __restrict__ xb,
                       int total4x) {
    int gb = blockIdx.x;
    if (gb == 0) {
        __shared__ int any;
        if (threadIdx.x == 0) any = 0;
        __syncthreads();
        if (ei[2 * threadIdx.x + 1] != 0) atomicOr(&any, 1);
        __syncthreads();
        if (threadIdx.x == 0) *flag = (any == 0);  // all-high-words-zero => int64
    } else if (gb <= 288) {
        int idx = (gb - 1) * 256 + threadIdx.x;
        if (idx < 128 * 64) {
            int c = idx >> 6, k = idx & 63;
            w1t[idx] = f2b(W1[k * 128 + c]);
        } else if (idx < 128 * 64 + 128 * 128) {
            int i = idx - 128 * 64; int c = i >> 7, k = i & 127;
            w2t[i] = f2b(W2[k * 128 + c]);
        } else if (idx < 128 * 64 + 128 * 128 + 128 * 384) {
            int i = idx - (128 * 64 + 128 * 128); int c = i / 384, k = i % 384;
            wmt[i] = f2b(Wm[k * 128 + c]);
        }
    } else {
        int i = (gb - 289) * 256 + threadIdx.x;
        if (i >= total4x) return;
        float4 v = ((const float4*)x)[i];
        ushort4 o;
        o.x = (unsigned short)f2b(v.x);
        o.y = (unsigned short)f2b(v.y);
        o.z = (unsigned short)f2b(v.z);
        o.w = (unsigned short)f2b(v.w);
        ((ushort4*)xb)[i] = o;
    }
}

// ---------------- pass 1: partition edges into (slot, dst>>9) cells ----------------
__global__ __launch_bounds__(256) void k_part(const int* __restrict__ ei,
        const float* __restrict__ ew, const int* __restrict__ flag,
        int* __restrict__ pcur, int2* __restrict__ part, int E, int NB) {
    __shared__ int lcnt[NBC];
    __shared__ int lbase[NBC];
    int t = threadIdx.x;
    int slot = blockIdx.x & 7;
    for (int i = t; i < NBC; i += 256) lcnt[i] = 0;
    __syncthreads();
    int e0 = blockIdx.x * 1024;
    bool f64 = (*flag != 0);
    int sv[4], bv[4], loc[4]; float wv[4];
#pragma unroll
    for (int q = 0; q < 4; ++q) {
        int e = e0 + q * 256 + t;
        if (e < E) {
            int s, d;
            if (f64) { s = ei[2 * e]; d = ei[2 * E + 2 * e]; }
            else     { s = ei[e];     d = ei[E + e]; }
            wv[q] = ew[e];
            bv[q] = d >> 9;
            loc[q] = atomicAdd(&lcnt[bv[q]], 1);
            sv[q] = s | ((d & 511) << 17);
        } else bv[q] = -1;
    }
    __syncthreads();
    if (t < NB && lcnt[t] > 0)
        lbase[t] = atomicAdd(&pcur[(slot * NB + t) * PST], lcnt[t]);
    __syncthreads();
#pragma unroll
    for (int q = 0; q < 4; ++q) {
        if (bv[q] < 0) continue;
        int pos = lbase[bv[q]] + loc[q];
        if (pos >= CAPP) continue;
        int2 rec;
        rec.x = sv[q];
        rec.y = __float_as_int(wv[q]);
        part[(size_t)(slot * NB + bv[q]) * CAPP + pos] = rec;
    }
}

// ---------------- bucket-base scan (1 block; NB <= 256) ----------------
__global__ void k_bscan(const int* __restrict__ pcur, int* __restrict__ bbase, int NB) {
    __shared__ int lds[256];
    int t = threadIdx.x;
    int tot = 0;
    if (t < NB)
        for (int s = 0; s < 8; ++s) tot += min(pcur[(s * NB + t) * PST], CAPP);
    lds[t] = tot;
    __syncthreads();
    for (int off = 1; off < 256; off <<= 1) {
        int v = (t >= off) ? lds[t - off] : 0;
        __syncthreads();
        lds[t] += v;
        __syncthreads();
    }
    if (t < NB) bbase[t] = lds[t] - tot;  // exclusive
}

// ---------------- pass 2a: per-bucket histogram -> rowptr/rowend/dinv ----------------
__global__ __launch_bounds__(256) void k_bstats(const int2* __restrict__ part,
        const int* __restrict__ pcur, const int* __restrict__ bbase,
        int* __restrict__ rowptr, int* __restrict__ rowend, float* __restrict__ dinv,
        int N, int NB) {
    __shared__ int cnt[512];
    __shared__ float deg[512];
    __shared__ int scn[512];
    int b = blockIdx.x;
    int t = threadIdx.x;
    cnt[t] = 0; cnt[t + 256] = 0;
    deg[t] = 0.f; deg[t + 256] = 0.f;
    __syncthreads();
    for (int slot = 0; slot < 8; ++slot) {
        int n = min(pcur[(slot * NB + b) * PST], CAPP);
        const int2* cell = part + (size_t)(slot * NB + b) * CAPP;
        for (int i = t; i < n; i += 256) {
            int2 r = cell[i];
            int dl = (unsigned)r.x >> 17;
            atomicAdd(&cnt[dl], 1);
            atomicAdd(&deg[dl], __int_as_float(r.y));
        }
    }
    __syncthreads();
    scn[t] = cnt[t]; scn[t + 256] = cnt[t + 256];
    __syncthreads();
    for (int off = 1; off < 512; off <<= 1) {
        int v0 = (t >= off) ? scn[t - off] : 0;
        int i1 = t + 256;
        int v1 = (i1 >= off) ? scn[i1 - off] : 0;
        __syncthreads();
        scn[t] += v0; scn[i1] += v1;
        __syncthreads();
    }
    int base = bbase[b];
    for (int l = t; l < 512; l += 256) {
        int node = (b << 9) + l;
        if (node < N) {
            int rp = base + scn[l] - cnt[l];
            rowptr[node] = rp;
            rowend[node] = rp + cnt[l];
            dinv[node] = rsqrtf(deg[l] + 1.0f);
        }
    }
}

// ---------------- pass 2b: per-bucket scatter into final CSR {src, norm} ----------------
__global__ __launch_bounds__(256) void k_bsort(const int2* __restrict__ part,
        const int* __restrict__ pcur, const int* __restrict__ rowptr,
        const float* __restrict__ dinvArr, int2* __restrict__ ecsr, int N, int NB) {
    __shared__ int lcur[512];
    __shared__ float ldinv[512];
    int b = blockIdx.x;
    int t = threadIdx.x;
    for (int l = t; l < 512; l += 256) {
        int node = (b << 9) + l;
        lcur[l] = (node < N) ? rowptr[node] : 0;
        ldinv[l] = (node < N) ? dinvArr[node] : 0.f;
    }
    __syncthreads();
    for (int slot = 0; slot < 8; ++slot) {
        int n = min(pcur[(slot * NB + b) * PST], CAPP);
        const int2* cell = part + (size_t)(slot * NB + b) * CAPP;
        for (int i = t; i < n; i += 256) {
            int2 r = cell[i];
            int dl = (unsigned)r.x >> 17;
            int s = r.x & 0x1FFFF;
            float w = __int_as_float(r.y);
            int pos = atomicAdd(&lcur[dl], 1);
            int2 o;
            o.x = s;
            o.y = __float_as_int(dinvArr[s] * w * ldinv[dl]);
            ecsr[pos] = o;
        }
    }
}

// ---------------- hybrid MFMA GEMM: B staged in LDS per 128-K chunk, A direct ----------------
// MODE 0: K=64  A=agg0 bf16; out bf16 + bias eb (b1); fused BN stats -> stats
// MODE 1: K=128 A=h1c bf16 + BN(stats,g,be)+ReLU in-reg; out bf16
// MODE 2: K=384 virtual (BN2ReLU(h2c) | dist-feat | degf-feat); out f32 + bias eb (bm)
template <int K, int MODE>
__global__ __launch_bounds__(256) void k_gemm(
        const unsigned short* __restrict__ A, const short* __restrict__ Bt,
        float* __restrict__ stats, const float* __restrict__ g,
        const float* __restrict__ be, const float* __restrict__ dist,
        const float* __restrict__ degf, const float* __restrict__ Wd,
        const float* __restrict__ bd, const float* __restrict__ Wg,
        const float* __restrict__ bg, const float* __restrict__ eb,
        void* __restrict__ out, int N, float invN) {
    constexpr int CH = (K < 128) ? K : 128;
    __shared__ short Bs[128][CH + 8];
    __shared__ float sc[128], sh[128];
    __shared__ float st0[128], st1[128];
    const int t = threadIdx.x;
    const int lane = t & 63;
    const int wave = t >> 6;
    const int rl = lane & 15;
    const int kg = lane >> 4;
    const int r0 = blockIdx.x * 128;

    if (MODE >= 1) {
        if (t < 128) {
            float mean = stats[t] * invN;
            float var = stats[128 + t] * invN - mean * mean;
            float scale = g[t] * rsqrtf(var + BN_EPS);
            sc[t] = scale;
            sh[t] = be[t] - mean * scale;
        }
    }
    if (MODE == 0) {
        if (t < 128) { st0[t] = 0.f; st1[t] = 0.f; }
    }

    f32x4 acc[2][8];
#pragma unroll
    for (int m = 0; m < 2; ++m)
#pragma unroll
        for (int n = 0; n < 8; ++n) acc[m][n] = (f32x4){0.f, 0.f, 0.f, 0.f};

    const int AST = (MODE == 0) ? 64 : 128;
    const int rowbase = r0 + wave * 32 + rl;

    for (int kc = 0; kc < K; kc += CH) {
        if (kc > 0) __syncthreads();
        {
            int c = t >> 1;
            int hb = (t & 1) * (CH / 2);
            const short* wrow = Bt + (size_t)c * K + kc + hb;
#pragma unroll
            for (int q = 0; q < CH / 16; ++q)
                *(int4*)&Bs[c][hb + q * 8] = ((const int4*)wrow)[q];
        }
        __syncthreads();
#pragma unroll
        for (int kt0 = 0; kt0 < CH; kt0 += 32) {
            const int kt = kc + kt0;
            const int k0 = kt + kg * 8;
            const int kl0 = kt0 + kg * 8;
            bf16x8 a[2];
#pragma unroll
            for (int m = 0; m < 2; ++m) {
                const int row = rowbase + m * 16;
                union { int4 q; unsigned short s[8]; } u;
                if (MODE == 2 && kt >= 128) {
                    if (row < N) {
                        const float* Wv; const float* bv; float sx; int cb;
                        if (kt >= 256) { Wv = Wg; bv = bg; sx = degf[row]; cb = k0 - 256; }
                        else           { Wv = Wd; bv = bd; sx = dist[row]; cb = k0 - 128; }
#pragma unroll
                        for (int j = 0; j < 8; ++j)
                            u.s[j] = (unsigned short)f2b(fmaxf(0.f, sx * Wv[cb + j] + bv[cb + j]));
                    } else u.q = (int4){0, 0, 0, 0};
                } else if (MODE == 0) {
                    u.q = (row < N) ? *(const int4*)(A + (size_t)row * AST + k0)
                                    : (int4){0, 0, 0, 0};
                } else {
                    if (row < N) {
                        union { int4 q; unsigned short s[8]; } raw;
                        raw.q = *(const int4*)(A + (size_t)row * AST + k0);
#pragma unroll
                        for (int j = 0; j < 8; ++j)
                            u.s[j] = (unsigned short)f2b(
                                fmaxf(0.f, bu2f(raw.s[j]) * sc[k0 + j] + sh[k0 + j]));
                    } else u.q = (int4){0, 0, 0, 0};
                }
                a[m] = *reinterpret_cast<bf16x8*>(&u);
            }
#pragma unroll
            for (int n = 0; n < 8; ++n) {
                bf16x8 b = *reinterpret_cast<const bf16x8*>(&Bs[n * 16 + rl][kl0]);
                acc[0][n] = __builtin_amdgcn_mfma_f32_16x16x32_bf16(a[0], b, acc[0][n], 0, 0, 0);
                acc[1][n] = __builtin_amdgcn_mfma_f32_16x16x32_bf16(a[1], b, acc[1][n], 0, 0, 0);
            }
        }
    }

    // epilogue (C/D: col=lane&15, row=(lane>>4)*4+reg; m89-verified)
    const int rbase = r0 + wave * 32 + kg * 4;
#pragma unroll
    for (int n = 0; n < 8; ++n) {
        int col = n * 16 + rl;
        float bias = (MODE != 1) ? eb[col] : 0.f;
        float sl = 0.f, ql = 0.f;
#pragma unroll
        for (int m = 0; m < 2; ++m) {
#pragma unroll
            for (int j = 0; j < 4; ++j) {
                int row = rbase + m * 16 + j;
                if (row < N) {
                    float val = acc[m][n][j] + bias;
                    if (MODE == 2) {
                        ((float*)out)[(size_t)row * 128 + col] = val;
                    } else {
                        ((unsigned short*)out)[(size_t)row * 128 + col] = (unsigned short)f2b(val);
                        if (MODE == 0) { sl += val; ql += val * val; }
                    }
                }
            }
        }
        if (MODE == 0) {
            atomicAdd(&st0[col], sl);
            atomicAdd(&st1[col], ql);
        }
    }
    if (MODE == 0) {
        __syncthreads();
        if (t < 128) {
            atomicAdd(&stats[t], st0[t]);
            atomicAdd(&stats[128 + t], st1[t]);
        }
    }
}

// ---------------- CSR gathers: quarter-wave edge assignment ----------------
// Each 16-lane quarter owns one edge; lane loads uint2 (4ch, gather64) or
// uint4 (8ch, gather128b) -> full row per quarter, 4 edges/wave-iter.
// Two shfl_xor (16,32) merge quarters; quarter 0 adds self+bias, writes row.
__global__ void k_gather64(const unsigned short* __restrict__ xb, const int2* __restrict__ ecsr,
                           const int* __restrict__ rowptr, const int* __restrict__ rowend,
                           const float* __restrict__ dinv, unsigned short* __restrict__ agg0,
                           int N) {
    int node = blockIdx.x * 4 + (threadIdx.x >> 6);
    if (node >= N) return;
    int lane = threadIdx.x & 63;
    int q = lane >> 4;
    int cl = lane & 15;
    const uint2* xt = (const uint2*)xb;   // uint2 = 4 channels; row = 16 uint2
    int start = rowptr[node], end = rowend[node];
    float a0 = 0.f, a1 = 0.f, a2 = 0.f, a3 = 0.f;
    int j = start + q;
    for (; j + 4 < end; j += 8) {
        int2 e0 = ecsr[j], e1 = ecsr[j + 4];
        uint2 v0 = xt[(size_t)e0.x * 16 + cl];
        uint2 v1 = xt[(size_t)e1.x * 16 + cl];
        float w0 = __int_as_float(e0.y), w1 = __int_as_float(e1.y);
        a0 += w0 * lo16(v0.x) + w1 * lo16(v1.x);
        a1 += w0 * hi16(v0.x) + w1 * hi16(v1.x);
        a2 += w0 * lo16(v0.y) + w1 * lo16(v1.y);
        a3 += w0 * hi16(v0.y) + w1 * hi16(v1.y);
    }
    for (; j < end; j += 4) {
        int2 e = ecsr[j];
        uint2 v = xt[(size_t)e.x * 16 + cl];
        float w = __int_as_float(e.y);
        a0 += w * lo16(v.x);
        a1 += w * hi16(v.x);
        a2 += w * lo16(v.y);
        a3 += w * hi16(v.y);
    }
    a0 += __shfl_xor(a0, 16); a0 += __shfl_xor(a0, 32);
    a1 += __shfl_xor(a1, 16); a1 += __shfl_xor(a1, 32);
    a2 += __shfl_xor(a2, 16); a2 += __shfl_xor(a2, 32);
    a3 += __shfl_xor(a3, 16); a3 += __shfl_xor(a3, 32);
    if (q == 0) {
        float di = dinv[node];
        float sl = di * di;
        uint2 hv = xt[(size_t)node * 16 + cl];
        a0 += sl * lo16(hv.x);
        a1 += sl * hi16(hv.x);
        a2 += sl * lo16(hv.y);
        a3 += sl * hi16(hv.y);
        uint2 o;
        o.x = pk2(a0, a1);
        o.y = pk2(a2, a3);
        ((uint2*)agg0)[(size_t)node * 16 + cl] = o;
    }
}

// lane loads uint4 = 8 channels; quarter-wave per edge; 4 edges/wave-iter.
__global__ void k_gather128b(const uint4* __restrict__ t2, const int2* __restrict__ ecsr,
                             const int* __restrict__ rowptr, const int* __restrict__ rowend,
                             const float* __restrict__ dinv, const float* __restrict__ bias,
                             uint4* __restrict__ h2c, int N) {
    int node = blockIdx.x * 4 + (threadIdx.x >> 6);
    if (node >= N) return;
    int lane = threadIdx.x & 63;
    int q = lane >> 4;
    int cl = lane & 15;
    int start = rowptr[node], end = rowend[node];
    float a0 = 0.f, a1 = 0.f, a2 = 0.f, a3 = 0.f;
    float a4 = 0.f, a5 = 0.f, a6 = 0.f, a7 = 0.f;
    int j = start + q;
    for (; j + 4 < end; j += 8) {
        int2 e0 = ecsr[j], e1 = ecsr[j + 4];
        uint4 v0 = t2[(size_t)e0.x * 16 + cl];
        uint4 v1 = t2[(size_t)e1.x * 16 + cl];
        float w0 = __int_as_float(e0.y), w1 = __int_as_float(e1.y);
        a0 += w0 * lo16(v0.x) + w1 * lo16(v1.x);
        a1 += w0 * hi16(v0.x) + w1 * hi16(v1.x);
        a2 += w0 * lo16(v0.y) + w1 * lo16(v1.y);
        a3 += w0 * hi16(v0.y) + w1 * hi16(v1.y);
        a4 += w0 * lo16(v0.z) + w1 * lo16(v1.z);
        a5 += w0 * hi16(v0.z) + w1 * hi16(v1.z);
        a6 += w0 * lo16(v0.w) + w1 * lo16(v1.w);
        a7 += w0 * hi16(v0.w) + w1 * hi16(v1.w);
    }
    for (; j < end; j += 4) {
        int2 e = ecsr[j];
        uint4 v = t2[(size_t)e.x * 16 + cl];
        float w = __int_as_float(e.y);
        a0 += w * lo16(v.x);
        a1 += w * hi16(v.x);
        a2 += w * lo16(v.y);
        a3 += w * hi16(v.y);
        a4 += w * lo16(v.z);
        a5 += w * hi16(v.z);
        a6 += w * lo16(v.w);
        a7 += w * hi16(v.w);
    }
    a0 += __shfl_xor(a0, 16); a0 += __shfl_xor(a0, 32);
    a1 += __shfl_xor(a1, 16); a1 += __shfl_xor(a1, 32);
    a2 += __shfl_xor(a2, 16); a2 += __shfl_xor(a2, 32);
    a3 += __shfl_xor(a3, 16); a3 += __shfl_xor(a3, 32);
    a4 += __shfl_xor(a4, 16); a4 += __shfl_xor(a4, 32);
    a5 += __shfl_xor(a5, 16); a5 += __shfl_xor(a5, 32);
    a6 += __shfl_xor(a6, 16); a6 += __shfl_xor(a6, 32);
    a7 += __shfl_xor(a7, 16); a7 += __shfl_xor(a7, 32);
    if (q == 0) {
        float di = dinv[node];
        float sl = di * di;
        uint4 hv = t2[(size_t)node * 16 + cl];
        float4 b0 = ((const float4*)bias)[2 * cl];
        float4 b1 = ((const float4*)bias)[2 * cl + 1];
        a0 += sl * lo16(hv.x) + b0.x;
        a1 += sl * hi16(hv.x) + b0.y;
        a2 += sl * lo16(hv.y) + b0.z;
        a3 += sl * hi16(hv.y) + b0.w;
        a4 += sl * lo16(hv.z) + b1.x;
        a5 += sl * hi16(hv.z) + b1.y;
        a6 += sl * lo16(hv.w) + b1.z;
        a7 += sl * hi16(hv.w) + b1.w;
        uint4 o;
        o.x = pk2(a0, a1);
        o.y = pk2(a2, a3);
        o.z = pk2(a4, a5);
        o.w = pk2(a6, a7);
        h2c[(size_t)node * 16 + cl] = o;
    }
}

// ---------------- BN2 stats: vectorized partials + final reduce ----------------
__global__ __launch_bounds__(256) void k_bn_partial(const uint4* __restrict__ h,
                                                    float* __restrict__ part, int total4) {
    __shared__ float sm[256];
    sm[threadIdx.x] = 0.f;
    __syncthreads();
    float s[8], q[8];
#pragma unroll
    for (int j = 0; j < 8; ++j) { s[j] = 0.f; q[j] = 0.f; }
    int stride = gridDim.x * 256;
    for (int i = blockIdx.x * 256 + threadIdx.x; i < total4; i += stride) {
        uint4 v = h[i];
        float a;
        a = lo16(v.x); s[0] += a; q[0] += a * a;
        a = hi16(v.x); s[1] += a; q[1] += a * a;
        a = lo16(v.y); s[2] += a; q[2] += a * a;
        a = hi16(v.y); s[3] += a; q[3] += a * a;
        a = lo16(v.z); s[4] += a; q[4] += a * a;
        a = hi16(v.z); s[5] += a; q[5] += a * a;
        a = lo16(v.w); s[6] += a; q[6] += a * a;
        a = hi16(v.w); s[7] += a; q[7] += a * a;
    }
    int c0 = 8 * (threadIdx.x & 15);
#pragma unroll
    for (int j = 0; j < 8; ++j) {
        atomicAdd(&sm[c0 + j], s[j]);
        atomicAdd(&sm[128 + c0 + j], q[j]);
    }
    __syncthreads();
    part[blockIdx.x * 256 + threadIdx.x] = sm[threadIdx.x];
}

__global__ void k_bn_reduce(const float* __restrict__ part, float* __restrict__ stats, int nb) {
    int t = threadIdx.x;
    float acc = 0.f;
#pragma unroll 4
    for (int b = 0; b < nb; ++b) acc += part[b * 256 + t];
    stats[t] = acc;
}

extern "C" void kernel_launch(void* const* d_in, const int* in_sizes, int n_in,
                              void* d_out, int out_size, void* d_ws, size_t ws_size,
                              hipStream_t stream) {
    const float* x    = (const float*)d_in[0];
    const int*   ei   = (const int*)d_in[1];
    const float* ew   = (const float*)d_in[2];
    const float* dist = (const float*)d_in[3];
    const float* degf = (const float*)d_in[4];
    const float* W1   = (const float*)d_in[5];
    const float* b1   = (const float*)d_in[6];
    const float* W2   = (const float*)d_in[7];
    const float* b2   = (const float*)d_in[8];
    const float* g1   = (const float*)d_in[9];
    const float* be1  = (const float*)d_in[10];
    const float* g2   = (const float*)d_in[11];
    const float* be2  = (const float*)d_in[12];
    const float* Wd   = (const float*)d_in[13];
    const float* bd   = (const float*)d_in[14];
    const float* Wg   = (const float*)d_in[15];
    const float* bg   = (const float*)d_in[16];
    const float* Wm   = (const float*)d_in[17];
    const float* bm   = (const float*)d_in[18];

    const int IN = 64;
    const int N = in_sizes[0] / IN;   // 100000
    const int E = in_sizes[1] / 2;    // 1600000
    const int NB = (N + 511) >> 9;    // 196 buckets (<= NBC)

    // ws layout (4B words):
    int*   pcur   = (int*)d_ws;                                      // [8*NBC*PST]
    float* stats  = (float*)(pcur + 8 * NBC * PST);                  // [512]
    int*   flag   = (int*)(stats + 512);
    int*   bbase  = flag + 32;                                       // [NBC]
    int*   rowptr = bbase + NBC;                                     // [N]
    int*   rowend = rowptr + N;                                      // [N]
    float* dinv   = (float*)(rowend + N);                            // [N]
    int2*  partb  = (int2*)(dinv + N);                               // [8*NBC*CAPP] int2
    int2*  ecsr   = partb + (size_t)8 * NBC * CAPP;                  // [E] int2
    unsigned int*   h2c  = (unsigned int*)(ecsr + E);                // N*128 bf16
    unsigned short* agg0 = (unsigned short*)(h2c + (size_t)N * 64);  // N*64 bf16
    unsigned short* xb   = agg0 + (size_t)N * 64;                    // N*64 bf16
    short* w1t    = (short*)(xb + (size_t)N * 64);                   // [128][64]
    short* w2t    = w1t + 128 * 64;                                  // [128][128]
    short* wmt    = w2t + 128 * 128;                                 // [128][384]
    float* bnpart = (float*)(wmt + 128 * 384);                       // [512][256]

    // d_out time-share (bf16 staging, overwritten by final f32 GEMM)
    unsigned short* h1c = (unsigned short*)d_out;                    // N*128 bf16
    unsigned int*   t2  = (unsigned int*)d_out + (size_t)N * 64;     // N*128 bf16 pairs

    hipMemsetAsync(pcur, 0, (8 * NBC * PST + 512) * sizeof(int), stream);

    const int nchunkP = (E + 1023) / 1024;
    const int nbG  = (N + 3) / 4;
    const int nbPrep = 1 + 288 + (N * 16 + 255) / 256;

    k_prep<<<nbPrep, 256, 0, stream>>>(ei, flag, W1, W2, Wm, w1t, w2t, wmt, x, xb, N * 16);
    k_part<<<nchunkP, 256, 0, stream>>>(ei, ew, flag, pcur, partb, E, NB);
    k_bscan<<<1, 256, 0, stream>>>(pcur, bbase, NB);
    k_bstats<<<NB, 256, 0, stream>>>(partb, pcur, bbase, rowptr, rowend, dinv, N, NB);
    k_bsort<<<NB, 256, 0, stream>>>(partb, pcur, rowptr, dinv, ecsr, N, NB);

    const int nbGe = (N + 127) / 128;
    const int nbP  = 512;
    const float invN = 1.0f / (float)N;

    // layer 1: agg0 = A_hat @ x; h1c = agg0 @ W1 + b1 (stats1 fused in epilogue)
    k_gather64<<<nbG, 256, 0, stream>>>(xb, ecsr, rowptr, rowend, dinv, agg0, N);
    k_gemm<64, 0><<<nbGe, 256, 0, stream>>>(agg0, w1t, stats, nullptr, nullptr, nullptr,
                                            nullptr, nullptr, nullptr, nullptr, nullptr,
                                            b1, h1c, N, invN);

    // layer 2: t2 = BN1ReLU(h1c) @ W2; h2c = A_hat @ t2 + b2; stats2 (two-stage)
    k_gemm<128, 1><<<nbGe, 256, 0, stream>>>(h1c, w2t, stats, g1, be1, nullptr,
                                             nullptr, nullptr, nullptr, nullptr, nullptr,
                                             nullptr, t2, N, invN);
    k_gather128b<<<nbG, 256, 0, stream>>>((const uint4*)t2, ecsr, rowptr, rowend, dinv,
                                          b2, (uint4*)h2c, N);
    k_bn_partial<<<nbP, 256, 0, stream>>>((const uint4*)h2c, bnpart, N * 16);
    k_bn_reduce<<<1, 256, 0, stream>>>(bnpart, stats + 256, nbP);

    // final: [BN2ReLU(h2c) | relu(dist*Wd+bd) | relu(degf*Wg+bg)] @ Wm + bm -> d_out f32
    k_gemm<384, 2><<<nbGe, 256, 0, stream>>>((const unsigned short*)h2c, wmt, stats + 256,
                                             g2, be2, dist, degf, Wd, bd, Wg, bg,
                                             bm, d_out, N, invN);
}